// Round 2
// baseline (292.254 us; speedup 1.0000x reference)
//
#include <hip/hip_runtime.h>
#include <hip/hip_bf16.h>
#include <math.h>

#define B_  32
#define C_  256
#define HW_ 4096
#define K_  5

typedef __hip_bfloat16 bf16;

// ---------- dtype-flexible load/store ----------
template<bool BF>
__device__ inline float LD(const void* p, size_t i) {
    if (BF) return __bfloat162float(((const bf16*)p)[i]);
    return ((const float*)p)[i];
}
template<bool BF>
__device__ inline void ST(void* p, size_t i, float v) {
    if (BF) ((bf16*)p)[i] = __float2bfloat16(v);
    else    ((float*)p)[i] = v;
}
template<bool BF>
__device__ inline float4 LD4(const void* p, size_t i) {   // i: element index, %4==0
    if (BF) {
        ushort4 u = *(const ushort4*)((const unsigned short*)p + i);
        float4 r;
        r.x = __uint_as_float(((unsigned)u.x) << 16);
        r.y = __uint_as_float(((unsigned)u.y) << 16);
        r.z = __uint_as_float(((unsigned)u.z) << 16);
        r.w = __uint_as_float(((unsigned)u.w) << 16);
        return r;
    }
    return *(const float4*)((const float*)p + i);
}
template<bool BF>
__device__ inline void ST4(void* p, size_t i, float4 v) {
    if (BF) {
        bf16 a = __float2bfloat16(v.x), b = __float2bfloat16(v.y),
             c = __float2bfloat16(v.z), d = __float2bfloat16(v.w);
        ushort4 u;
        u.x = *(unsigned short*)&a; u.y = *(unsigned short*)&b;
        u.z = *(unsigned short*)&c; u.w = *(unsigned short*)&d;
        *(ushort4*)((unsigned short*)p + i) = u;
    } else {
        *(float4*)((float*)p + i) = v;
    }
}

// ---------- block reductions (256 threads = 4 waves) ----------
__device__ inline float blk_sum(float v, float* sh) {
    for (int o = 32; o > 0; o >>= 1) v += __shfl_down(v, o, 64);
    int w = threadIdx.x >> 6;
    __syncthreads();
    if ((threadIdx.x & 63) == 0) sh[w] = v;
    __syncthreads();
    return sh[0] + sh[1] + sh[2] + sh[3];
}
__device__ inline float blk_max(float v, float* sh) {
    for (int o = 32; o > 0; o >>= 1) v = fmaxf(v, __shfl_down(v, o, 64));
    int w = threadIdx.x >> 6;
    __syncthreads();
    if ((threadIdx.x & 63) == 0) sh[w] = v;
    __syncthreads();
    return fmaxf(fmaxf(sh[0], sh[1]), fmaxf(sh[2], sh[3]));
}

// ---------- 0: dtype detect + part_queries normalize (1 block) ----------
template<bool BF>
__device__ void qnorm_body(const void* pq, float* qn, float* sh) {
    int t = threadIdx.x;  // t == c
    for (int k = 0; k < K_; k++) {
        float v = LD<BF>(pq, (size_t)k * C_ + t);
        float ss = blk_sum(v * v, sh);
        float inv = 1.0f / fmaxf(sqrtf(ss), 1e-12f);
        qn[k * C_ + t] = v * inv;
    }
}
__global__ void k_init(const void* feat, const void* pq, float* qn, int* flag) {
    __shared__ int cnt;
    __shared__ int flg;
    __shared__ float sh[4];
    int t = threadIdx.x;
    if (t == 0) cnt = 0;
    __syncthreads();
    const unsigned short* u = (const unsigned short*)feat;
    int local = 0;
    for (int i = t; i < 4096; i += 256) {
        float v = __uint_as_float(((unsigned)u[i]) << 16);
        float a = fabsf(v);
        if (a >= 1e-4f && a <= 100.f) local++;
    }
    atomicAdd(&cnt, local);
    __syncthreads();
    if (t == 0) { flg = (cnt > 3072) ? 1 : 0; *flag = flg; }
    __syncthreads();
    if (flg) qnorm_body<true>(pq, qn, sh); else qnorm_body<false>(pq, qn, sh);
}

// ---------- 1: sim = masked (qn . feat/||feat||)/temp  [64 thr, 4 pos/thr] ----------
template<bool BF>
__device__ void sim_body(const void* feat, const void* mask, const void* temp,
                         const float* qn, float* sim, float* qL) {
    int t = threadIdx.x;
    int b = blockIdx.y;
    int n = blockIdx.x * 256 + t * 4;
    for (int i = t; i < K_ * C_; i += 64) qL[i] = qn[i];
    __syncthreads();
    float tinv = 1.0f / fmaxf(LD<BF>(temp, 0), 0.01f);
    size_t base = (size_t)b * C_ * HW_ + n;
    float4 ss = make_float4(0, 0, 0, 0);
    float4 d[K_];
    #pragma unroll
    for (int k = 0; k < K_; k++) d[k] = make_float4(0, 0, 0, 0);
    #pragma unroll 8
    for (int c = 0; c < C_; c++) {
        float4 f = LD4<BF>(feat, base + (size_t)c * HW_);
        ss.x += f.x * f.x; ss.y += f.y * f.y; ss.z += f.z * f.z; ss.w += f.w * f.w;
        #pragma unroll
        for (int k = 0; k < K_; k++) {
            float q = qL[k * C_ + c];
            d[k].x += f.x * q; d[k].y += f.y * q; d[k].z += f.z * q; d[k].w += f.w * q;
        }
    }
    float4 m4 = LD4<BF>(mask, (size_t)b * HW_ + n);
    float4 sc;
    sc.x = tinv / fmaxf(sqrtf(ss.x), 1e-12f);
    sc.y = tinv / fmaxf(sqrtf(ss.y), 1e-12f);
    sc.z = tinv / fmaxf(sqrtf(ss.z), 1e-12f);
    sc.w = tinv / fmaxf(sqrtf(ss.w), 1e-12f);
    size_t sb = (size_t)b * K_ * HW_ + n;
    #pragma unroll
    for (int k = 0; k < K_; k++) {
        float4 o;
        o.x = (m4.x > 0.f) ? d[k].x * sc.x : -INFINITY;
        o.y = (m4.y > 0.f) ? d[k].y * sc.y : -INFINITY;
        o.z = (m4.z > 0.f) ? d[k].z * sc.z : -INFINITY;
        o.w = (m4.w > 0.f) ? d[k].w * sc.w : -INFINITY;
        *(float4*)(sim + sb + (size_t)k * HW_) = o;
    }
}
__global__ __launch_bounds__(64, 1) void k_sim(const int* flag, const void* feat,
                                               const void* mask, const void* temp,
                                               const float* qn, float* sim) {
    __shared__ __attribute__((aligned(16))) float qL[K_ * C_];
    if (*flag) sim_body<true>(feat, mask, temp, qn, sim, qL);
    else       sim_body<false>(feat, mask, temp, qn, sim, qL);
}

// ---------- 2: softmax over n per (b,k), in place ----------
__global__ void k_softmax(float* sim) {
    __shared__ float sh[4];
    int t = threadIdx.x;
    float* p = sim + (size_t)blockIdx.x * HW_;
    float4 v[4];
    float mx = -INFINITY;
    #pragma unroll
    for (int i = 0; i < 4; i++) {
        v[i] = *(float4*)(p + t * 4 + i * 1024);
        mx = fmaxf(mx, fmaxf(fmaxf(v[i].x, v[i].y), fmaxf(v[i].z, v[i].w)));
    }
    mx = blk_max(mx, sh);
    if (mx == -INFINITY) {
        float4 z = make_float4(0, 0, 0, 0);
        #pragma unroll
        for (int i = 0; i < 4; i++) *(float4*)(p + t * 4 + i * 1024) = z;
        return;
    }
    float s = 0;
    #pragma unroll
    for (int i = 0; i < 4; i++) {
        v[i].x = __expf(v[i].x - mx); v[i].y = __expf(v[i].y - mx);
        v[i].z = __expf(v[i].z - mx); v[i].w = __expf(v[i].w - mx);
        s += v[i].x + v[i].y + v[i].z + v[i].w;
    }
    s = blk_sum(s, sh);
    float inv = 1.0f / s;
    #pragma unroll
    for (int i = 0; i < 4; i++) {
        v[i].x *= inv; v[i].y *= inv; v[i].z *= inv; v[i].w *= inv;
        *(float4*)(p + t * 4 + i * 1024) = v[i];
    }
}

// ---------- 3: part_tokens[b,k,c] = sum_n attn*feat  [8-c tile/block] ----------
#define CT_ 8
template<bool BF>
__device__ void pt_body(const void* feat, const float* attn, float* pt, float* red) {
    int t = threadIdx.x, b = blockIdx.y, c0 = blockIdx.x * CT_;
    int lane = t & 63, w = t >> 6;
    float acc[CT_ * K_];
    #pragma unroll
    for (int j = 0; j < CT_ * K_; j++) acc[j] = 0.f;
    size_t fb = ((size_t)b * C_ + c0) * HW_;
    size_t ab = (size_t)b * K_ * HW_;
    #pragma unroll
    for (int i = 0; i < 4; i++) {
        int n = t * 4 + i * 1024;
        float4 a4[K_];
        #pragma unroll
        for (int k = 0; k < K_; k++) a4[k] = *(const float4*)(attn + ab + (size_t)k * HW_ + n);
        #pragma unroll
        for (int cc = 0; cc < CT_; cc++) {
            float4 f = LD4<BF>(feat, fb + (size_t)cc * HW_ + n);
            #pragma unroll
            for (int k = 0; k < K_; k++)
                acc[cc * K_ + k] += f.x * a4[k].x + f.y * a4[k].y + f.z * a4[k].z + f.w * a4[k].w;
        }
    }
    #pragma unroll
    for (int j = 0; j < CT_ * K_; j++) {
        float v = acc[j];
        for (int o = 32; o > 0; o >>= 1) v += __shfl_down(v, o, 64);
        if (lane == 0) red[w * CT_ * K_ + j] = v;
    }
    __syncthreads();
    if (t < CT_ * K_) {
        float s = red[t] + red[CT_ * K_ + t] + red[2 * CT_ * K_ + t] + red[3 * CT_ * K_ + t];
        int cc = t / K_, k = t % K_;
        pt[((size_t)b * K_ + k) * C_ + c0 + cc] = s;
    }
}
__global__ void k_pt(const int* flag, const void* feat, const float* attn, float* pt) {
    __shared__ float red[4 * CT_ * K_];
    if (*flag) pt_body<true>(feat, attn, pt, red); else pt_body<false>(feat, attn, pt, red);
}

// ---------- 4: prep (W2, b2, OV per b,k) + diversity partials, merged grid ----------
template<bool BF>
__device__ void prep_body(const void* qw, const void* kw, const void* kb,
                          const void* vw, const void* vb, const void* ow,
                          const void* bnw, const void* bnb, const void* bnm, const void* bnv,
                          const float* pt, float* W2, float* b2, float* OV, float* smem) {
    float* ptL = smem;            // 256
    float* KtL = smem + 256;      // 256 (pre-scaled by bn scale)
    float* VtL = smem + 512;      // 256
    float* sh  = smem + 768;      // 4
    int bk = blockIdx.x, t = threadIdx.x;
    ptL[t] = pt[(size_t)bk * C_ + t];
    __syncthreads();
    float kt = LD<BF>(kb, t), vt = LD<BF>(vb, t);
    for (int c = 0; c < C_; c += 4) {
        float4 p4 = *(float4*)(ptL + c);
        float4 kw4 = LD4<BF>(kw, (size_t)t * C_ + c);
        float4 vw4 = LD4<BF>(vw, (size_t)t * C_ + c);
        kt += kw4.x * p4.x + kw4.y * p4.y + kw4.z * p4.z + kw4.w * p4.w;
        vt += vw4.x * p4.x + vw4.y * p4.y + vw4.z * p4.z + vw4.w * p4.w;
    }
    float scale = LD<BF>(bnw, t) * rsqrtf(LD<BF>(bnv, t) + 1e-5f);
    float shift = LD<BF>(bnb, t) - LD<BF>(bnm, t) * scale;
    KtL[t] = kt * scale;
    VtL[t] = vt;
    float bpart = kt * shift;
    __syncthreads();
    float ov = 0;
    for (int c = 0; c < C_; c += 4) {
        float4 v4 = *(float4*)(VtL + c);
        float4 ow4 = LD4<BF>(ow, (size_t)t * C_ + c);
        ov += ow4.x * v4.x + ow4.y * v4.y + ow4.z * v4.z + ow4.w * v4.w;
    }
    OV[(size_t)bk * C_ + t] = ov;
    float w2 = 0;
    for (int o = 0; o < C_; o++) w2 += KtL[o] * LD<BF>(qw, (size_t)o * C_ + t);
    W2[(size_t)bk * C_ + t] = w2 * (1.0f / 16.0f);
    float bs = blk_sum(bpart, sh);
    if (t == 0) b2[bk] = bs * (1.0f / 16.0f);
}
template<bool BF>
__device__ void div_body(const float* pt, const void* margin, float* divpart, float* smem) {
    float* ptL = smem;                 // 1280
    float* rn  = smem + K_ * C_;       // 5
    float* sh  = rn + 8;               // 4
    int b = blockIdx.x - 160, t = threadIdx.x;
    for (int i = t; i < K_ * C_; i += 256) ptL[i] = pt[(size_t)b * K_ * C_ + i];
    __syncthreads();
    for (int k = 0; k < K_; k++) {
        float v = ptL[k * C_ + t];
        float s = blk_sum(v * v, sh);
        if (t == 0) rn[k] = 1.0f / fmaxf(sqrtf(s), 1e-12f);
    }
    __syncthreads();
    float m = LD<BF>(margin, 0);
    m = fminf(fmaxf(m, 0.f), 0.5f);
    int p = t >> 3, g = t & 7;
    float contrib = 0.f;
    if (p < K_ * K_) {
        int k = p / K_, j = p % K_;
        float d = 0;
        for (int c = g; c < C_; c += 8) d += ptL[k * C_ + c] * ptL[j * C_ + c];
        d += __shfl_down(d, 4, 8);
        d += __shfl_down(d, 2, 8);
        d += __shfl_down(d, 1, 8);
        if (g == 0 && k != j) contrib = fmaxf(d * rn[k] * rn[j] - m, 0.f);
    }
    float s = blk_sum(contrib, sh);
    if (t == 0) divpart[b] = s;
}
__global__ void k_prepdiv(const int* flag, const void* qw, const void* kw, const void* kb,
                          const void* vw, const void* vb, const void* ow,
                          const void* bnw, const void* bnb, const void* bnm, const void* bnv,
                          const float* pt, const void* margin,
                          float* W2, float* b2, float* OV, float* divpart) {
    __shared__ __attribute__((aligned(16))) float smem[K_ * C_ + 16];
    if (blockIdx.x < 160) {
        if (*flag) prep_body<true >(qw, kw, kb, vw, vb, ow, bnw, bnb, bnm, bnv, pt, W2, b2, OV, smem);
        else       prep_body<false>(qw, kw, kb, vw, vb, ow, bnw, bnb, bnm, bnv, pt, W2, b2, OV, smem);
    } else {
        if (*flag) div_body<true >(pt, margin, divpart, smem);
        else       div_body<false>(pt, margin, divpart, smem);
    }
}

// ---------- 5: fused refine-attention + residual + aux writer ----------
template<bool BF>
__device__ void fin_body(const void* feat, const void* outb, const void* gamma,
                         const float* W2, const float* b2, const float* OV,
                         const float* pt, const float* divpart,
                         void* dout, float* smem) {
    float* W2L = smem;                  // 1280
    float* OVL = smem + K_ * C_;        // 1280
    float* obL = OVL + K_ * C_;         // 256
    float* b2L = obL + C_;              // 5
    int t = threadIdx.x, b = blockIdx.y;
    int n = blockIdx.x * 256 + t * 4;
    for (int i = t; i < K_ * C_; i += 64) {
        W2L[i] = W2[(size_t)b * K_ * C_ + i];
        OVL[i] = OV[(size_t)b * K_ * C_ + i];
    }
    for (int i = t; i < C_; i += 64) obL[i] = LD<BF>(outb, i);
    if (t < K_) b2L[t] = b2[b * K_ + t];
    __syncthreads();
    float g = LD<BF>(gamma, 0);
    size_t base = (size_t)b * C_ * HW_ + n;
    float4 l[K_];
    #pragma unroll
    for (int k = 0; k < K_; k++) l[k] = make_float4(b2L[k], b2L[k], b2L[k], b2L[k]);
    #pragma unroll 8
    for (int c = 0; c < C_; c++) {
        float4 f = LD4<BF>(feat, base + (size_t)c * HW_);
        #pragma unroll
        for (int k = 0; k < K_; k++) {
            float wv = W2L[k * C_ + c];
            l[k].x += f.x * wv; l[k].y += f.y * wv; l[k].z += f.z * wv; l[k].w += f.w * wv;
        }
    }
    float4 mx = l[0];
    #pragma unroll
    for (int k = 1; k < K_; k++) {
        mx.x = fmaxf(mx.x, l[k].x); mx.y = fmaxf(mx.y, l[k].y);
        mx.z = fmaxf(mx.z, l[k].z); mx.w = fmaxf(mx.w, l[k].w);
    }
    float4 sum = make_float4(0, 0, 0, 0);
    #pragma unroll
    for (int k = 0; k < K_; k++) {
        l[k].x = __expf(l[k].x - mx.x); l[k].y = __expf(l[k].y - mx.y);
        l[k].z = __expf(l[k].z - mx.z); l[k].w = __expf(l[k].w - mx.w);
        sum.x += l[k].x; sum.y += l[k].y; sum.z += l[k].z; sum.w += l[k].w;
    }
    sum.x = 1.0f / sum.x; sum.y = 1.0f / sum.y; sum.z = 1.0f / sum.z; sum.w = 1.0f / sum.w;
    #pragma unroll
    for (int k = 0; k < K_; k++) {
        l[k].x *= sum.x; l[k].y *= sum.y; l[k].z *= sum.z; l[k].w *= sum.w;
    }
    #pragma unroll 4
    for (int o = 0; o < C_; o++) {
        float4 f = LD4<BF>(feat, base + (size_t)o * HW_);
        float ob = obL[o];
        float4 a = make_float4(ob, ob, ob, ob);
        #pragma unroll
        for (int k = 0; k < K_; k++) {
            float ovv = OVL[k * C_ + o];
            a.x += l[k].x * ovv; a.y += l[k].y * ovv; a.z += l[k].z * ovv; a.w += l[k].w * ovv;
        }
        f.x += g * a.x; f.y += g * a.y; f.z += g * a.z; f.w += g * a.w;
        ST4<BF>(dout, base + (size_t)o * HW_, f);
    }
    // aux outputs: part_tokens + div_loss, done by the b==0 slice of the grid
    if (b == 0) {
        const size_t enh = (size_t)B_ * C_ * HW_;
        for (int i = blockIdx.x * 64 + t; i < B_ * K_ * C_; i += 16 * 64)
            ST<BF>(dout, enh + 1 + i, pt[i]);
        if (blockIdx.x == 0 && t == 0) {
            float s = 0;
            for (int bb = 0; bb < B_; bb++) s += divpart[bb];
            ST<BF>(dout, enh, s / (640.0f + 1e-5f));
        }
    }
}
__global__ __launch_bounds__(64, 1) void k_fin(const int* flag, const void* feat,
                                               const void* outb, const void* gamma,
                                               const float* W2, const float* b2, const float* OV,
                                               const float* pt, const float* divpart, void* dout) {
    __shared__ __attribute__((aligned(16))) float smem[2 * K_ * C_ + C_ + 8];
    if (*flag) fin_body<true >(feat, outb, gamma, W2, b2, OV, pt, divpart, dout, smem);
    else       fin_body<false>(feat, outb, gamma, W2, b2, OV, pt, divpart, dout, smem);
}

extern "C" void kernel_launch(void* const* d_in, const int* in_sizes, int n_in,
                              void* d_out, int out_size, void* d_ws, size_t ws_size,
                              hipStream_t stream) {
    const void* feat = d_in[0];
    const void* mask = d_in[1];
    const void* pq   = d_in[2];
    const void* temp = d_in[3];
    const void* marg = d_in[4];
    const void* qw   = d_in[5];
    const void* bnw  = d_in[6];
    const void* bnb  = d_in[7];
    const void* bnm  = d_in[8];
    const void* bnv  = d_in[9];
    const void* kw   = d_in[10];
    const void* kb   = d_in[11];
    const void* vw   = d_in[12];
    const void* vb   = d_in[13];
    const void* ow   = d_in[14];
    const void* ob   = d_in[15];
    const void* gm   = d_in[16];

    float* ws  = (float*)d_ws;
    float* sim = ws;                            // B*K*HW = 655360
    float* pt  = sim + (size_t)B_ * K_ * HW_;   // 40960
    float* qn  = pt  + B_ * K_ * C_;            // 1280
    float* W2  = qn  + K_ * C_;                 // 40960
    float* b2  = W2  + B_ * K_ * C_;            // 160
    float* OV  = b2  + B_ * K_;                 // 40960
    float* dvp = OV  + B_ * K_ * C_;            // 32
    int*  flag = (int*)(dvp + B_);

    hipLaunchKernelGGL(k_init, dim3(1), dim3(256), 0, stream, feat, pq, qn, flag);
    hipLaunchKernelGGL(k_sim, dim3(HW_ / 256, B_), dim3(64), 0, stream,
                       flag, feat, mask, temp, qn, sim);
    hipLaunchKernelGGL(k_softmax, dim3(B_ * K_), dim3(256), 0, stream, sim);
    hipLaunchKernelGGL(k_pt, dim3(C_ / CT_, B_), dim3(256), 0, stream, flag, feat, sim, pt);
    hipLaunchKernelGGL(k_prepdiv, dim3(160 + B_), dim3(256), 0, stream,
                       flag, qw, kw, kb, vw, vb, ow, bnw, bnb, bnm, bnv, pt, marg,
                       W2, b2, OV, dvp);
    hipLaunchKernelGGL(k_fin, dim3(HW_ / 256, B_), dim3(64), 0, stream,
                       flag, feat, ob, gm, W2, b2, OV, pt, dvp, d_out);
}

// Round 3
// 232.477 us; speedup vs baseline: 1.2571x; 1.2571x over previous
//
#include <hip/hip_runtime.h>
#include <hip/hip_bf16.h>
#include <math.h>

#define B_  32
#define C_  256
#define HW_ 4096
#define K_  5

typedef __hip_bfloat16 bf16;

// ---------- dtype-flexible load/store ----------
template<bool BF>
__device__ inline float LD(const void* p, size_t i) {
    if (BF) return __bfloat162float(((const bf16*)p)[i]);
    return ((const float*)p)[i];
}
template<bool BF>
__device__ inline void ST(void* p, size_t i, float v) {
    if (BF) ((bf16*)p)[i] = __float2bfloat16(v);
    else    ((float*)p)[i] = v;
}
template<bool BF>
__device__ inline float4 LD4(const void* p, size_t i) {   // i: element index, %4==0
    if (BF) {
        ushort4 u = *(const ushort4*)((const unsigned short*)p + i);
        float4 r;
        r.x = __uint_as_float(((unsigned)u.x) << 16);
        r.y = __uint_as_float(((unsigned)u.y) << 16);
        r.z = __uint_as_float(((unsigned)u.z) << 16);
        r.w = __uint_as_float(((unsigned)u.w) << 16);
        return r;
    }
    return *(const float4*)((const float*)p + i);
}
template<bool BF>
__device__ inline void ST4(void* p, size_t i, float4 v) {
    if (BF) {
        bf16 a = __float2bfloat16(v.x), b = __float2bfloat16(v.y),
             c = __float2bfloat16(v.z), d = __float2bfloat16(v.w);
        ushort4 u;
        u.x = *(unsigned short*)&a; u.y = *(unsigned short*)&b;
        u.z = *(unsigned short*)&c; u.w = *(unsigned short*)&d;
        *(ushort4*)((unsigned short*)p + i) = u;
    } else {
        *(float4*)((float*)p + i) = v;
    }
}

// ---------- block reductions (256 threads = 4 waves) ----------
__device__ inline float blk_sum(float v, float* sh) {
    for (int o = 32; o > 0; o >>= 1) v += __shfl_down(v, o, 64);
    int w = threadIdx.x >> 6;
    __syncthreads();
    if ((threadIdx.x & 63) == 0) sh[w] = v;
    __syncthreads();
    return sh[0] + sh[1] + sh[2] + sh[3];
}
__device__ inline float blk_max(float v, float* sh) {
    for (int o = 32; o > 0; o >>= 1) v = fmaxf(v, __shfl_down(v, o, 64));
    int w = threadIdx.x >> 6;
    __syncthreads();
    if ((threadIdx.x & 63) == 0) sh[w] = v;
    __syncthreads();
    return fmaxf(fmaxf(sh[0], sh[1]), fmaxf(sh[2], sh[3]));
}

// ---------- 0: dtype detect + part_queries normalize (1 block, 256 thr) ----------
template<bool BF>
__device__ void qnorm_body(const void* pq, float* qn, float* sh) {
    int t = threadIdx.x;  // t == c
    for (int k = 0; k < K_; k++) {
        float v = LD<BF>(pq, (size_t)k * C_ + t);
        float ss = blk_sum(v * v, sh);
        float inv = 1.0f / fmaxf(sqrtf(ss), 1e-12f);
        qn[k * C_ + t] = v * inv;
    }
}
__global__ void k_init(const void* feat, const void* pq, float* qn, int* flag) {
    __shared__ int cnt;
    __shared__ int flg;
    __shared__ float sh[4];
    int t = threadIdx.x;
    if (t == 0) cnt = 0;
    __syncthreads();
    const unsigned short* u = (const unsigned short*)feat;
    int local = 0;
    for (int i = t; i < 4096; i += 256) {
        float v = __uint_as_float(((unsigned)u[i]) << 16);
        float a = fabsf(v);
        if (a >= 1e-4f && a <= 100.f) local++;
    }
    atomicAdd(&cnt, local);
    __syncthreads();
    if (t == 0) { flg = (cnt > 3072) ? 1 : 0; *flag = flg; }
    __syncthreads();
    if (flg) qnorm_body<true>(pq, qn, sh); else qnorm_body<false>(pq, qn, sh);
}

// ---------- 1: sim  [512 thr: 8 waves x 32-channel slices, 256 pos/block] ----------
template<bool BF>
__device__ void sim_body(const void* feat, const void* mask, const void* temp,
                         const float* qn, float* sim, float* qL, float* red) {
    int t = threadIdx.x;
    int lane = t & 63, q = t >> 6;
    int b = blockIdx.y;
    int n0 = blockIdx.x * 256 + lane * 4;
    for (int i = t; i < K_ * C_; i += 512) qL[i] = qn[i];
    __syncthreads();
    size_t base = (size_t)b * C_ * HW_ + n0;
    float sa[4] = {0.f, 0.f, 0.f, 0.f};
    float da[K_][4];
    #pragma unroll
    for (int k = 0; k < K_; k++)
        #pragma unroll
        for (int i = 0; i < 4; i++) da[k][i] = 0.f;
    int c0 = q * 32;
    #pragma unroll 8
    for (int cc = 0; cc < 32; cc++) {
        int c = c0 + cc;
        float4 f = LD4<BF>(feat, base + (size_t)c * HW_);
        sa[0] += f.x * f.x; sa[1] += f.y * f.y; sa[2] += f.z * f.z; sa[3] += f.w * f.w;
        #pragma unroll
        for (int k = 0; k < K_; k++) {
            float qv = qL[k * C_ + c];
            da[k][0] += f.x * qv; da[k][1] += f.y * qv;
            da[k][2] += f.z * qv; da[k][3] += f.w * qv;
        }
    }
    #pragma unroll
    for (int i = 0; i < 4; i++) {
        red[(i * 6 + 0) * 512 + t] = sa[i];
        #pragma unroll
        for (int k = 0; k < K_; k++) red[(i * 6 + 1 + k) * 512 + t] = da[k][i];
    }
    __syncthreads();
    if (q < K_) {   // wave q finalizes + stores sim row k=q
        float tinv = 1.0f / fmaxf(LD<BF>(temp, 0), 0.01f);
        float4 m4 = LD4<BF>(mask, (size_t)b * HW_ + n0);
        float mv[4] = {m4.x, m4.y, m4.z, m4.w};
        float out[4];
        #pragma unroll
        for (int i = 0; i < 4; i++) {
            float ssum = 0.f, dsum = 0.f;
            #pragma unroll
            for (int g = 0; g < 8; g++) {
                ssum += red[(i * 6 + 0) * 512 + g * 64 + lane];
                dsum += red[(i * 6 + 1 + q) * 512 + g * 64 + lane];
            }
            out[i] = (mv[i] > 0.f) ? dsum * (tinv / fmaxf(sqrtf(ssum), 1e-12f))
                                   : -INFINITY;
        }
        *(float4*)(sim + (size_t)b * K_ * HW_ + (size_t)q * HW_ + n0) =
            make_float4(out[0], out[1], out[2], out[3]);
    }
}
__global__ __launch_bounds__(512, 4) void k_sim(const int* flag, const void* feat,
                                                const void* mask, const void* temp,
                                                const float* qn, float* sim) {
    __shared__ __attribute__((aligned(16))) float qL[K_ * C_];
    __shared__ __attribute__((aligned(16))) float red[24 * 512];
    if (*flag) sim_body<true>(feat, mask, temp, qn, sim, qL, red);
    else       sim_body<false>(feat, mask, temp, qn, sim, qL, red);
}

// ---------- 2: softmax over n per (b,k), in place ----------
__global__ void k_softmax(float* sim) {
    __shared__ float sh[4];
    int t = threadIdx.x;
    float* p = sim + (size_t)blockIdx.x * HW_;
    float4 v[4];
    float mx = -INFINITY;
    #pragma unroll
    for (int i = 0; i < 4; i++) {
        v[i] = *(float4*)(p + t * 4 + i * 1024);
        mx = fmaxf(mx, fmaxf(fmaxf(v[i].x, v[i].y), fmaxf(v[i].z, v[i].w)));
    }
    mx = blk_max(mx, sh);
    if (mx == -INFINITY) {
        float4 z = make_float4(0, 0, 0, 0);
        #pragma unroll
        for (int i = 0; i < 4; i++) *(float4*)(p + t * 4 + i * 1024) = z;
        return;
    }
    float s = 0;
    #pragma unroll
    for (int i = 0; i < 4; i++) {
        v[i].x = __expf(v[i].x - mx); v[i].y = __expf(v[i].y - mx);
        v[i].z = __expf(v[i].z - mx); v[i].w = __expf(v[i].w - mx);
        s += v[i].x + v[i].y + v[i].z + v[i].w;
    }
    s = blk_sum(s, sh);
    float inv = 1.0f / s;
    #pragma unroll
    for (int i = 0; i < 4; i++) {
        v[i].x *= inv; v[i].y *= inv; v[i].z *= inv; v[i].w *= inv;
        *(float4*)(p + t * 4 + i * 1024) = v[i];
    }
}

// ---------- 3: part_tokens[b,k,c] = sum_n attn*feat  [8-c tile/block] ----------
#define CT_ 8
template<bool BF>
__device__ void pt_body(const void* feat, const float* attn, float* pt, float* red) {
    int t = threadIdx.x, b = blockIdx.y, c0 = blockIdx.x * CT_;
    int lane = t & 63, w = t >> 6;
    float acc[CT_ * K_];
    #pragma unroll
    for (int j = 0; j < CT_ * K_; j++) acc[j] = 0.f;
    size_t fb = ((size_t)b * C_ + c0) * HW_;
    size_t ab = (size_t)b * K_ * HW_;
    #pragma unroll
    for (int i = 0; i < 4; i++) {
        int n = t * 4 + i * 1024;
        float4 a4[K_];
        #pragma unroll
        for (int k = 0; k < K_; k++) a4[k] = *(const float4*)(attn + ab + (size_t)k * HW_ + n);
        #pragma unroll
        for (int cc = 0; cc < CT_; cc++) {
            float4 f = LD4<BF>(feat, fb + (size_t)cc * HW_ + n);
            #pragma unroll
            for (int k = 0; k < K_; k++)
                acc[cc * K_ + k] += f.x * a4[k].x + f.y * a4[k].y + f.z * a4[k].z + f.w * a4[k].w;
        }
    }
    #pragma unroll
    for (int j = 0; j < CT_ * K_; j++) {
        float v = acc[j];
        for (int o = 32; o > 0; o >>= 1) v += __shfl_down(v, o, 64);
        if (lane == 0) red[w * CT_ * K_ + j] = v;
    }
    __syncthreads();
    if (t < CT_ * K_) {
        float s = red[t] + red[CT_ * K_ + t] + red[2 * CT_ * K_ + t] + red[3 * CT_ * K_ + t];
        int cc = t / K_, k = t % K_;
        pt[((size_t)b * K_ + k) * C_ + c0 + cc] = s;
    }
}
__global__ __launch_bounds__(256, 4) void k_pt(const int* flag, const void* feat,
                                               const float* attn, float* pt) {
    __shared__ float red[4 * CT_ * K_];
    if (*flag) pt_body<true>(feat, attn, pt, red); else pt_body<false>(feat, attn, pt, red);
}

// ---------- 4: prep (W2, b2, OV per b,k) + diversity partials, merged grid ----------
template<bool BF>
__device__ void prep_body(const void* qw, const void* kw, const void* kb,
                          const void* vw, const void* vb, const void* ow,
                          const void* bnw, const void* bnb, const void* bnm, const void* bnv,
                          const float* pt, float* W2, float* b2, float* OV, float* smem) {
    float* ptL = smem;            // 256
    float* KtL = smem + 256;      // 256 (pre-scaled by bn scale)
    float* VtL = smem + 512;      // 256
    float* sh  = smem + 768;      // 4
    int bk = blockIdx.x, t = threadIdx.x;
    ptL[t] = pt[(size_t)bk * C_ + t];
    __syncthreads();
    float kt = LD<BF>(kb, t), vt = LD<BF>(vb, t);
    for (int c = 0; c < C_; c += 4) {
        float4 p4 = *(float4*)(ptL + c);
        float4 kw4 = LD4<BF>(kw, (size_t)t * C_ + c);
        float4 vw4 = LD4<BF>(vw, (size_t)t * C_ + c);
        kt += kw4.x * p4.x + kw4.y * p4.y + kw4.z * p4.z + kw4.w * p4.w;
        vt += vw4.x * p4.x + vw4.y * p4.y + vw4.z * p4.z + vw4.w * p4.w;
    }
    float scale = LD<BF>(bnw, t) * rsqrtf(LD<BF>(bnv, t) + 1e-5f);
    float shift = LD<BF>(bnb, t) - LD<BF>(bnm, t) * scale;
    KtL[t] = kt * scale;
    VtL[t] = vt;
    float bpart = kt * shift;
    __syncthreads();
    float ov = 0;
    for (int c = 0; c < C_; c += 4) {
        float4 v4 = *(float4*)(VtL + c);
        float4 ow4 = LD4<BF>(ow, (size_t)t * C_ + c);
        ov += ow4.x * v4.x + ow4.y * v4.y + ow4.z * v4.z + ow4.w * v4.w;
    }
    OV[(size_t)bk * C_ + t] = ov;
    float w2 = 0;
    for (int o = 0; o < C_; o++) w2 += KtL[o] * LD<BF>(qw, (size_t)o * C_ + t);
    W2[(size_t)bk * C_ + t] = w2 * (1.0f / 16.0f);
    float bs = blk_sum(bpart, sh);
    if (t == 0) b2[bk] = bs * (1.0f / 16.0f);
}
template<bool BF>
__device__ void div_body(const float* pt, const void* margin, float* divpart, float* smem) {
    float* ptL = smem;                 // 1280
    float* rn  = smem + K_ * C_;       // 5
    float* sh  = rn + 8;               // 4
    int b = blockIdx.x - 160, t = threadIdx.x;
    for (int i = t; i < K_ * C_; i += 256) ptL[i] = pt[(size_t)b * K_ * C_ + i];
    __syncthreads();
    for (int k = 0; k < K_; k++) {
        float v = ptL[k * C_ + t];
        float s = blk_sum(v * v, sh);
        if (t == 0) rn[k] = 1.0f / fmaxf(sqrtf(s), 1e-12f);
    }
    __syncthreads();
    float m = LD<BF>(margin, 0);
    m = fminf(fmaxf(m, 0.f), 0.5f);
    int p = t >> 3, g = t & 7;
    float contrib = 0.f;
    if (p < K_ * K_) {
        int k = p / K_, j = p % K_;
        float d = 0;
        for (int c = g; c < C_; c += 8) d += ptL[k * C_ + c] * ptL[j * C_ + c];
        d += __shfl_down(d, 4, 8);
        d += __shfl_down(d, 2, 8);
        d += __shfl_down(d, 1, 8);
        if (g == 0 && k != j) contrib = fmaxf(d * rn[k] * rn[j] - m, 0.f);
    }
    float s = blk_sum(contrib, sh);
    if (t == 0) divpart[b] = s;
}
__global__ void k_prepdiv(const int* flag, const void* qw, const void* kw, const void* kb,
                          const void* vw, const void* vb, const void* ow,
                          const void* bnw, const void* bnb, const void* bnm, const void* bnv,
                          const float* pt, const void* margin,
                          float* W2, float* b2, float* OV, float* divpart) {
    __shared__ __attribute__((aligned(16))) float smem[K_ * C_ + 16];
    if (blockIdx.x < 160) {
        if (*flag) prep_body<true >(qw, kw, kb, vw, vb, ow, bnw, bnb, bnm, bnv, pt, W2, b2, OV, smem);
        else       prep_body<false>(qw, kw, kb, vw, vb, ow, bnw, bnb, bnm, bnv, pt, W2, b2, OV, smem);
    } else {
        if (*flag) div_body<true >(pt, margin, divpart, smem);
        else       div_body<false>(pt, margin, divpart, smem);
    }
}

// ---------- 5: fused refine-attn + residual  [512 thr, 8-way channel split] ----------
template<bool BF>
__device__ void fin_body(const void* feat, const void* outb, const void* gamma,
                         const float* W2, const float* b2, const float* OV,
                         const float* pt, const float* divpart,
                         void* dout, float* smem) {
    float* W2L  = smem;                 // 1280
    float* OVL  = W2L + K_ * C_;        // 1280
    float* obL  = OVL + K_ * C_;        // 256
    float* b2L  = obL + C_;             // 8
    float* totl = b2L + 8;              // 5*256 = 1280
    float* red  = totl + K_ * 256;      // 20*512 = 10240
    int t = threadIdx.x, lane = t & 63, q = t >> 6;
    int b = blockIdx.y;
    int n0 = blockIdx.x * 256 + lane * 4;
    for (int i = t; i < K_ * C_; i += 512) {
        W2L[i] = W2[(size_t)b * K_ * C_ + i];
        OVL[i] = OV[(size_t)b * K_ * C_ + i];
    }
    for (int i = t; i < C_; i += 512) obL[i] = LD<BF>(outb, i);
    if (t < K_) b2L[t] = b2[b * K_ + t];
    __syncthreads();
    size_t base = (size_t)b * C_ * HW_ + n0;
    int c0 = q * 32;
    // phase 1: partial logits over this wave's 32 channels
    float la[K_][4];
    #pragma unroll
    for (int k = 0; k < K_; k++)
        #pragma unroll
        for (int i = 0; i < 4; i++) la[k][i] = 0.f;
    #pragma unroll 8
    for (int cc = 0; cc < 32; cc++) {
        int c = c0 + cc;
        float4 f = LD4<BF>(feat, base + (size_t)c * HW_);
        #pragma unroll
        for (int k = 0; k < K_; k++) {
            float wv = W2L[k * C_ + c];
            la[k][0] += f.x * wv; la[k][1] += f.y * wv;
            la[k][2] += f.z * wv; la[k][3] += f.w * wv;
        }
    }
    #pragma unroll
    for (int i = 0; i < 4; i++)
        #pragma unroll
        for (int k = 0; k < K_; k++) red[(i * 5 + k) * 512 + t] = la[k][i];
    __syncthreads();
    // stage A: 256 threads reduce 8 partials + bias per (position, k)
    if (t < 256) {
        int i = t & 3, Ls = t >> 2;
        #pragma unroll
        for (int k = 0; k < K_; k++) {
            float s = b2L[k];
            #pragma unroll
            for (int g = 0; g < 8; g++) s += red[(i * 5 + k) * 512 + g * 64 + Ls];
            totl[k * 256 + t] = s;
        }
    }
    __syncthreads();
    // stage B: per-position softmax (each thread, its 4 positions)
    float e[K_][4];
    #pragma unroll
    for (int i = 0; i < 4; i++) {
        int p = lane * 4 + i;
        float l0 = totl[0 * 256 + p], l1 = totl[1 * 256 + p], l2 = totl[2 * 256 + p],
              l3 = totl[3 * 256 + p], l4 = totl[4 * 256 + p];
        float mx = fmaxf(fmaxf(fmaxf(l0, l1), fmaxf(l2, l3)), l4);
        float e0 = __expf(l0 - mx), e1 = __expf(l1 - mx), e2 = __expf(l2 - mx),
              e3 = __expf(l3 - mx), e4 = __expf(l4 - mx);
        float inv = 1.0f / (e0 + e1 + e2 + e3 + e4);
        e[0][i] = e0 * inv; e[1][i] = e1 * inv; e[2][i] = e2 * inv;
        e[3][i] = e3 * inv; e[4][i] = e4 * inv;
    }
    // phase 2: output over this wave's 32 channels
    float g = LD<BF>(gamma, 0);
    #pragma unroll 4
    for (int oo = 0; oo < 32; oo++) {
        int o = c0 + oo;
        float4 f = LD4<BF>(feat, base + (size_t)o * HW_);
        float ob = obL[o];
        float4 a = make_float4(ob, ob, ob, ob);
        #pragma unroll
        for (int k = 0; k < K_; k++) {
            float ovv = OVL[k * C_ + o];
            a.x += e[k][0] * ovv; a.y += e[k][1] * ovv;
            a.z += e[k][2] * ovv; a.w += e[k][3] * ovv;
        }
        f.x += g * a.x; f.y += g * a.y; f.z += g * a.z; f.w += g * a.w;
        ST4<BF>(dout, base + (size_t)o * HW_, f);
    }
    // aux outputs: part_tokens + div_loss (b==0 slice of grid)
    if (b == 0) {
        const size_t enh = (size_t)B_ * C_ * HW_;
        for (int i = blockIdx.x * 512 + t; i < B_ * K_ * C_; i += 16 * 512)
            ST<BF>(dout, enh + 1 + i, pt[i]);
        if (blockIdx.x == 0 && t == 0) {
            float s = 0;
            for (int bb = 0; bb < B_; bb++) s += divpart[bb];
            ST<BF>(dout, enh, s / (640.0f + 1e-5f));
        }
    }
}
__global__ __launch_bounds__(512, 4) void k_fin(const int* flag, const void* feat,
                                                const void* outb, const void* gamma,
                                                const float* W2, const float* b2, const float* OV,
                                                const float* pt, const float* divpart, void* dout) {
    __shared__ __attribute__((aligned(16)))
        float smem[2 * K_ * C_ + C_ + 8 + K_ * 256 + 20 * 512];
    if (*flag) fin_body<true >(feat, outb, gamma, W2, b2, OV, pt, divpart, dout, smem);
    else       fin_body<false>(feat, outb, gamma, W2, b2, OV, pt, divpart, dout, smem);
}

extern "C" void kernel_launch(void* const* d_in, const int* in_sizes, int n_in,
                              void* d_out, int out_size, void* d_ws, size_t ws_size,
                              hipStream_t stream) {
    const void* feat = d_in[0];
    const void* mask = d_in[1];
    const void* pq   = d_in[2];
    const void* temp = d_in[3];
    const void* marg = d_in[4];
    const void* qw   = d_in[5];
    const void* bnw  = d_in[6];
    const void* bnb  = d_in[7];
    const void* bnm  = d_in[8];
    const void* bnv  = d_in[9];
    const void* kw   = d_in[10];
    const void* kb   = d_in[11];
    const void* vw   = d_in[12];
    const void* vb   = d_in[13];
    const void* ow   = d_in[14];
    const void* ob   = d_in[15];
    const void* gm   = d_in[16];

    float* ws  = (float*)d_ws;
    float* sim = ws;                            // B*K*HW = 655360
    float* pt  = sim + (size_t)B_ * K_ * HW_;   // 40960
    float* qn  = pt  + B_ * K_ * C_;            // 1280
    float* W2  = qn  + K_ * C_;                 // 40960
    float* b2  = W2  + B_ * K_ * C_;            // 160
    float* OV  = b2  + B_ * K_;                 // 40960
    float* dvp = OV  + B_ * K_ * C_;            // 32
    int*  flag = (int*)(dvp + B_);

    hipLaunchKernelGGL(k_init, dim3(1), dim3(256), 0, stream, feat, pq, qn, flag);
    hipLaunchKernelGGL(k_sim, dim3(HW_ / 256, B_), dim3(512), 0, stream,
                       flag, feat, mask, temp, qn, sim);
    hipLaunchKernelGGL(k_softmax, dim3(B_ * K_), dim3(256), 0, stream, sim);
    hipLaunchKernelGGL(k_pt, dim3(C_ / CT_, B_), dim3(256), 0, stream, flag, feat, sim, pt);
    hipLaunchKernelGGL(k_prepdiv, dim3(160 + B_), dim3(256), 0, stream,
                       flag, qw, kw, kb, vw, vb, ow, bnw, bnb, bnm, bnv, pt, marg,
                       W2, b2, OV, dvp);
    hipLaunchKernelGGL(k_fin, dim3(HW_ / 256, B_), dim3(512), 0, stream,
                       flag, feat, ob, gm, W2, b2, OV, pt, dvp, d_out);
}

// Round 4
// 186.096 us; speedup vs baseline: 1.5704x; 1.2492x over previous
//
#include <hip/hip_runtime.h>
#include <hip/hip_bf16.h>
#include <math.h>

#define B_  32
#define C_  256
#define HW_ 4096
#define K_  5
#define NT_ 16          // n-tiles per batch (256 positions each)

typedef __hip_bfloat16 bf16;

// ---------- dtype-flexible load/store ----------
template<bool BF>
__device__ inline float LD(const void* p, size_t i) {
    if (BF) return __bfloat162float(((const bf16*)p)[i]);
    return ((const float*)p)[i];
}
template<bool BF>
__device__ inline void ST(void* p, size_t i, float v) {
    if (BF) ((bf16*)p)[i] = __float2bfloat16(v);
    else    ((float*)p)[i] = v;
}
template<bool BF>
__device__ inline float4 LD4(const void* p, size_t i) {   // i: element index, %4==0
    if (BF) {
        ushort4 u = *(const ushort4*)((const unsigned short*)p + i);
        float4 r;
        r.x = __uint_as_float(((unsigned)u.x) << 16);
        r.y = __uint_as_float(((unsigned)u.y) << 16);
        r.z = __uint_as_float(((unsigned)u.z) << 16);
        r.w = __uint_as_float(((unsigned)u.w) << 16);
        return r;
    }
    return *(const float4*)((const float*)p + i);
}
template<bool BF>
__device__ inline void ST4(void* p, size_t i, float4 v) {
    if (BF) {
        bf16 a = __float2bfloat16(v.x), b = __float2bfloat16(v.y),
             c = __float2bfloat16(v.z), d = __float2bfloat16(v.w);
        ushort4 u;
        u.x = *(unsigned short*)&a; u.y = *(unsigned short*)&b;
        u.z = *(unsigned short*)&c; u.w = *(unsigned short*)&d;
        *(ushort4*)((unsigned short*)p + i) = u;
    } else {
        *(float4*)((float*)p + i) = v;
    }
}

// ---------- block reductions (256 threads = 4 waves) ----------
__device__ inline float blk_sum(float v, float* sh) {
    for (int o = 32; o > 0; o >>= 1) v += __shfl_down(v, o, 64);
    int w = threadIdx.x >> 6;
    __syncthreads();
    if ((threadIdx.x & 63) == 0) sh[w] = v;
    __syncthreads();
    return sh[0] + sh[1] + sh[2] + sh[3];
}

// ---------- 0: dtype detect + part_queries normalize (1 block, 256 thr) ----------
template<bool BF>
__device__ void qnorm_body(const void* pq, float* qn, float* sh) {
    int t = threadIdx.x;  // t == c
    for (int k = 0; k < K_; k++) {
        float v = LD<BF>(pq, (size_t)k * C_ + t);
        float ss = blk_sum(v * v, sh);
        float inv = 1.0f / fmaxf(sqrtf(ss), 1e-12f);
        qn[k * C_ + t] = v * inv;
    }
}
__global__ void k_init(const void* feat, const void* pq, float* qn, int* flag) {
    __shared__ int cnt;
    __shared__ int flg;
    __shared__ float sh[4];
    int t = threadIdx.x;
    if (t == 0) cnt = 0;
    __syncthreads();
    const unsigned short* u = (const unsigned short*)feat;
    int local = 0;
    for (int i = t; i < 4096; i += 256) {
        float v = __uint_as_float(((unsigned)u[i]) << 16);
        float a = fabsf(v);
        if (a >= 1e-4f && a <= 100.f) local++;
    }
    atomicAdd(&cnt, local);
    __syncthreads();
    if (t == 0) { flg = (cnt > 3072) ? 1 : 0; *flag = flg; }
    __syncthreads();
    if (flg) qnorm_body<true>(pq, qn, sh); else qnorm_body<false>(pq, qn, sh);
}

// ---------- 1: FUSED sim + block softmax partial + pt partial ----------
// block: 512 thr (8 waves), tile = 256 positions of batch b.
// phase 1: 8-way channel split computes per-position ss + 5 dots (LDS reduce).
// waves 0..4 finalize sim for k=q, wave-local max/Z, weights e -> LDS.
// phase 2: same feat addresses re-read (L2-warm), shuffle-reduced into ptp.
template<bool BF>
__device__ void simpt_body(const void* feat, const void* mask, const void* temp,
                           const float* qn, float* ptp, float* mz,
                           float* qL, float* red, float* wL) {
    int t = threadIdx.x;
    int lane = t & 63, q = t >> 6;
    int b = blockIdx.y, tile = blockIdx.x;
    int n0 = tile * 256 + lane * 4;
    for (int i = t; i < K_ * C_; i += 512) qL[i] = qn[i];
    __syncthreads();
    size_t base = (size_t)b * C_ * HW_ + n0;
    int c0 = q * 32;
    // phase 1: partial ss + dots over this wave's 32 channels
    float sa[4] = {0.f, 0.f, 0.f, 0.f};
    float da[K_][4];
    #pragma unroll
    for (int k = 0; k < K_; k++)
        #pragma unroll
        for (int i = 0; i < 4; i++) da[k][i] = 0.f;
    #pragma unroll 8
    for (int cc = 0; cc < 32; cc++) {
        int c = c0 + cc;
        float4 f = LD4<BF>(feat, base + (size_t)c * HW_);
        sa[0] += f.x * f.x; sa[1] += f.y * f.y; sa[2] += f.z * f.z; sa[3] += f.w * f.w;
        #pragma unroll
        for (int k = 0; k < K_; k++) {
            float qv = qL[k * C_ + c];
            da[k][0] += f.x * qv; da[k][1] += f.y * qv;
            da[k][2] += f.z * qv; da[k][3] += f.w * qv;
        }
    }
    #pragma unroll
    for (int i = 0; i < 4; i++) {
        red[(i * 6 + 0) * 512 + t] = sa[i];
        #pragma unroll
        for (int k = 0; k < K_; k++) red[(i * 6 + 1 + k) * 512 + t] = da[k][i];
    }
    __syncthreads();
    if (q < K_) {   // wave q: finalize sim row k=q for the 256 positions
        float tinv = 1.0f / fmaxf(LD<BF>(temp, 0), 0.01f);
        float4 m4 = LD4<BF>(mask, (size_t)b * HW_ + n0);
        float mv[4] = {m4.x, m4.y, m4.z, m4.w};
        float sv[4];
        #pragma unroll
        for (int i = 0; i < 4; i++) {
            float ssum = 0.f, dsum = 0.f;
            #pragma unroll
            for (int g = 0; g < 8; g++) {
                ssum += red[(i * 6 + 0) * 512 + g * 64 + lane];
                dsum += red[(i * 6 + 1 + q) * 512 + g * 64 + lane];
            }
            sv[i] = (mv[i] > 0.f) ? dsum * (tinv / fmaxf(sqrtf(ssum), 1e-12f))
                                  : -INFINITY;
        }
        // wave-local softmax partial (256 positions)
        float m = fmaxf(fmaxf(sv[0], sv[1]), fmaxf(sv[2], sv[3]));
        for (int o = 32; o > 0; o >>= 1) m = fmaxf(m, __shfl_xor(m, o, 64));
        float z = 0.f;
        #pragma unroll
        for (int i = 0; i < 4; i++) {
            float e = (sv[i] == -INFINITY) ? 0.f : __expf(sv[i] - m);
            wL[q * 256 + lane * 4 + i] = e;
            z += e;
        }
        for (int o = 32; o > 0; o >>= 1) z += __shfl_xor(z, o, 64);
        if (lane == 0) {
            size_t mzb = ((size_t)(b * NT_ + tile) * K_ + q) * 2;
            mz[mzb] = m; mz[mzb + 1] = z;
        }
    }
    __syncthreads();
    // phase 2: weighted accumulation over same 32 channels (feat L2-warm)
    float wv[K_][4];
    #pragma unroll
    for (int k = 0; k < K_; k++)
        #pragma unroll
        for (int i = 0; i < 4; i++) wv[k][i] = wL[k * 256 + lane * 4 + i];
    size_t pb = ((size_t)(b * NT_ + tile) * K_) * C_;
    #pragma unroll 4
    for (int cc = 0; cc < 32; cc++) {
        int c = c0 + cc;
        float4 f = LD4<BF>(feat, base + (size_t)c * HW_);
        float p[K_];
        #pragma unroll
        for (int k = 0; k < K_; k++)
            p[k] = f.x * wv[k][0] + f.y * wv[k][1] + f.z * wv[k][2] + f.w * wv[k][3];
        #pragma unroll
        for (int k = 0; k < K_; k++)
            for (int o = 32; o > 0; o >>= 1) p[k] += __shfl_down(p[k], o, 64);
        if (lane == 0) {
            #pragma unroll
            for (int k = 0; k < K_; k++) ptp[pb + (size_t)k * C_ + c] = p[k];
        }
    }
}
__global__ __launch_bounds__(512, 4) void k_simpt(const int* flag, const void* feat,
                                                  const void* mask, const void* temp,
                                                  const float* qn, float* ptp, float* mz) {
    __shared__ __attribute__((aligned(16))) float qL[K_ * C_];
    __shared__ __attribute__((aligned(16))) float red[24 * 512];
    __shared__ __attribute__((aligned(16))) float wL[K_ * 256];
    if (*flag) simpt_body<true >(feat, mask, temp, qn, ptp, mz, qL, red, wL);
    else       simpt_body<false>(feat, mask, temp, qn, ptp, mz, qL, red, wL);
}

// ---------- 2: merge tile partials -> part_tokens ----------
__global__ void k_merge(const float* ptp, const float* mz, float* pt) {
    int b = blockIdx.x, t = threadIdx.x;   // t == c
    #pragma unroll
    for (int k = 0; k < K_; k++) {
        float M = -INFINITY;
        #pragma unroll
        for (int tl = 0; tl < NT_; tl++)
            M = fmaxf(M, mz[((size_t)(b * NT_ + tl) * K_ + k) * 2]);
        float Zs = 0.f, acc = 0.f;
        #pragma unroll
        for (int tl = 0; tl < NT_; tl++) {
            size_t mzb = ((size_t)(b * NT_ + tl) * K_ + k) * 2;
            float m_t = mz[mzb], z_t = mz[mzb + 1];
            float s = (m_t == -INFINITY) ? 0.f : __expf(m_t - M);
            Zs += z_t * s;
            acc += ptp[((size_t)(b * NT_ + tl) * K_ + k) * C_ + t] * s;
        }
        pt[((size_t)b * K_ + k) * C_ + t] = (Zs > 0.f) ? acc / Zs : 0.f;
    }
}

// ---------- 3: prep (W2, b2, OV per b,k) + diversity partials, merged grid ----------
template<bool BF>
__device__ void prep_body(const void* qw, const void* kw, const void* kb,
                          const void* vw, const void* vb, const void* ow,
                          const void* bnw, const void* bnb, const void* bnm, const void* bnv,
                          const float* pt, float* W2, float* b2, float* OV, float* smem) {
    float* ptL = smem;            // 256
    float* KtL = smem + 256;      // 256 (pre-scaled by bn scale)
    float* VtL = smem + 512;      // 256
    float* sh  = smem + 768;      // 4
    int bk = blockIdx.x, t = threadIdx.x;
    ptL[t] = pt[(size_t)bk * C_ + t];
    __syncthreads();
    float kt = LD<BF>(kb, t), vt = LD<BF>(vb, t);
    for (int c = 0; c < C_; c += 4) {
        float4 p4 = *(float4*)(ptL + c);
        float4 kw4 = LD4<BF>(kw, (size_t)t * C_ + c);
        float4 vw4 = LD4<BF>(vw, (size_t)t * C_ + c);
        kt += kw4.x * p4.x + kw4.y * p4.y + kw4.z * p4.z + kw4.w * p4.w;
        vt += vw4.x * p4.x + vw4.y * p4.y + vw4.z * p4.z + vw4.w * p4.w;
    }
    float scale = LD<BF>(bnw, t) * rsqrtf(LD<BF>(bnv, t) + 1e-5f);
    float shift = LD<BF>(bnb, t) - LD<BF>(bnm, t) * scale;
    KtL[t] = kt * scale;
    VtL[t] = vt;
    float bpart = kt * shift;
    __syncthreads();
    float ov = 0;
    for (int c = 0; c < C_; c += 4) {
        float4 v4 = *(float4*)(VtL + c);
        float4 ow4 = LD4<BF>(ow, (size_t)t * C_ + c);
        ov += ow4.x * v4.x + ow4.y * v4.y + ow4.z * v4.z + ow4.w * v4.w;
    }
    OV[(size_t)bk * C_ + t] = ov;
    float w2 = 0;
    for (int o = 0; o < C_; o++) w2 += KtL[o] * LD<BF>(qw, (size_t)o * C_ + t);
    W2[(size_t)bk * C_ + t] = w2 * (1.0f / 16.0f);
    float bs = blk_sum(bpart, sh);
    if (t == 0) b2[bk] = bs * (1.0f / 16.0f);
}
template<bool BF>
__device__ void div_body(const float* pt, const void* margin, float* divpart, float* smem) {
    float* ptL = smem;                 // 1280
    float* rn  = smem + K_ * C_;       // 5
    float* sh  = rn + 8;               // 4
    int b = blockIdx.x - 160, t = threadIdx.x;
    for (int i = t; i < K_ * C_; i += 256) ptL[i] = pt[(size_t)b * K_ * C_ + i];
    __syncthreads();
    for (int k = 0; k < K_; k++) {
        float v = ptL[k * C_ + t];
        float s = blk_sum(v * v, sh);
        if (t == 0) rn[k] = 1.0f / fmaxf(sqrtf(s), 1e-12f);
    }
    __syncthreads();
    float m = LD<BF>(margin, 0);
    m = fminf(fmaxf(m, 0.f), 0.5f);
    int p = t >> 3, g = t & 7;
    float contrib = 0.f;
    if (p < K_ * K_) {
        int k = p / K_, j = p % K_;
        float d = 0;
        for (int c = g; c < C_; c += 8) d += ptL[k * C_ + c] * ptL[j * C_ + c];
        d += __shfl_down(d, 4, 8);
        d += __shfl_down(d, 2, 8);
        d += __shfl_down(d, 1, 8);
        if (g == 0 && k != j) contrib = fmaxf(d * rn[k] * rn[j] - m, 0.f);
    }
    float s = blk_sum(contrib, sh);
    if (t == 0) divpart[b] = s;
}
__global__ void k_prepdiv(const int* flag, const void* qw, const void* kw, const void* kb,
                          const void* vw, const void* vb, const void* ow,
                          const void* bnw, const void* bnb, const void* bnm, const void* bnv,
                          const float* pt, const void* margin,
                          float* W2, float* b2, float* OV, float* divpart) {
    __shared__ __attribute__((aligned(16))) float smem[K_ * C_ + 16];
    if (blockIdx.x < 160) {
        if (*flag) prep_body<true >(qw, kw, kb, vw, vb, ow, bnw, bnb, bnm, bnv, pt, W2, b2, OV, smem);
        else       prep_body<false>(qw, kw, kb, vw, vb, ow, bnw, bnb, bnm, bnv, pt, W2, b2, OV, smem);
    } else {
        if (*flag) div_body<true >(pt, margin, divpart, smem);
        else       div_body<false>(pt, margin, divpart, smem);
    }
}

// ---------- 4: fused refine-attn + residual  [512 thr, 8-way channel split] ----------
template<bool BF>
__device__ void fin_body(const void* feat, const void* outb, const void* gamma,
                         const float* W2, const float* b2, const float* OV,
                         const float* pt, const float* divpart,
                         void* dout, float* smem) {
    float* W2L  = smem;                 // 1280
    float* OVL  = W2L + K_ * C_;        // 1280
    float* obL  = OVL + K_ * C_;        // 256
    float* b2L  = obL + C_;             // 8
    float* totl = b2L + 8;              // 5*256 = 1280
    float* red  = totl + K_ * 256;      // 20*512 = 10240
    int t = threadIdx.x, lane = t & 63, q = t >> 6;
    int b = blockIdx.y;
    int n0 = blockIdx.x * 256 + lane * 4;
    for (int i = t; i < K_ * C_; i += 512) {
        W2L[i] = W2[(size_t)b * K_ * C_ + i];
        OVL[i] = OV[(size_t)b * K_ * C_ + i];
    }
    for (int i = t; i < C_; i += 512) obL[i] = LD<BF>(outb, i);
    if (t < K_) b2L[t] = b2[b * K_ + t];
    __syncthreads();
    size_t base = (size_t)b * C_ * HW_ + n0;
    int c0 = q * 32;
    // phase 1: partial logits over this wave's 32 channels
    float la[K_][4];
    #pragma unroll
    for (int k = 0; k < K_; k++)
        #pragma unroll
        for (int i = 0; i < 4; i++) la[k][i] = 0.f;
    #pragma unroll 8
    for (int cc = 0; cc < 32; cc++) {
        int c = c0 + cc;
        float4 f = LD4<BF>(feat, base + (size_t)c * HW_);
        #pragma unroll
        for (int k = 0; k < K_; k++) {
            float wv = W2L[k * C_ + c];
            la[k][0] += f.x * wv; la[k][1] += f.y * wv;
            la[k][2] += f.z * wv; la[k][3] += f.w * wv;
        }
    }
    #pragma unroll
    for (int i = 0; i < 4; i++)
        #pragma unroll
        for (int k = 0; k < K_; k++) red[(i * 5 + k) * 512 + t] = la[k][i];
    __syncthreads();
    // stage A: 256 threads reduce 8 partials + bias per (position, k)
    if (t < 256) {
        int i = t & 3, Ls = t >> 2;
        #pragma unroll
        for (int k = 0; k < K_; k++) {
            float s = b2L[k];
            #pragma unroll
            for (int g = 0; g < 8; g++) s += red[(i * 5 + k) * 512 + g * 64 + Ls];
            totl[k * 256 + t] = s;
        }
    }
    __syncthreads();
    // stage B: per-position softmax (each thread, its 4 positions)
    float e[K_][4];
    #pragma unroll
    for (int i = 0; i < 4; i++) {
        int p = lane * 4 + i;
        float l0 = totl[0 * 256 + p], l1 = totl[1 * 256 + p], l2 = totl[2 * 256 + p],
              l3 = totl[3 * 256 + p], l4 = totl[4 * 256 + p];
        float mx = fmaxf(fmaxf(fmaxf(l0, l1), fmaxf(l2, l3)), l4);
        float e0 = __expf(l0 - mx), e1 = __expf(l1 - mx), e2 = __expf(l2 - mx),
              e3 = __expf(l3 - mx), e4 = __expf(l4 - mx);
        float inv = 1.0f / (e0 + e1 + e2 + e3 + e4);
        e[0][i] = e0 * inv; e[1][i] = e1 * inv; e[2][i] = e2 * inv;
        e[3][i] = e3 * inv; e[4][i] = e4 * inv;
    }
    // phase 2: output over this wave's 32 channels
    float g = LD<BF>(gamma, 0);
    #pragma unroll 4
    for (int oo = 0; oo < 32; oo++) {
        int o = c0 + oo;
        float4 f = LD4<BF>(feat, base + (size_t)o * HW_);
        float ob = obL[o];
        float4 a = make_float4(ob, ob, ob, ob);
        #pragma unroll
        for (int k = 0; k < K_; k++) {
            float ovv = OVL[k * C_ + o];
            a.x += e[k][0] * ovv; a.y += e[k][1] * ovv;
            a.z += e[k][2] * ovv; a.w += e[k][3] * ovv;
        }
        f.x += g * a.x; f.y += g * a.y; f.z += g * a.z; f.w += g * a.w;
        ST4<BF>(dout, base + (size_t)o * HW_, f);
    }
    // aux outputs: part_tokens + div_loss (b==0 slice of grid)
    if (b == 0) {
        const size_t enh = (size_t)B_ * C_ * HW_;
        for (int i = blockIdx.x * 512 + t; i < B_ * K_ * C_; i += 16 * 512)
            ST<BF>(dout, enh + 1 + i, pt[i]);
        if (blockIdx.x == 0 && t == 0) {
            float s = 0;
            for (int bb = 0; bb < B_; bb++) s += divpart[bb];
            ST<BF>(dout, enh, s / (640.0f + 1e-5f));
        }
    }
}
__global__ __launch_bounds__(512, 4) void k_fin(const int* flag, const void* feat,
                                                const void* outb, const void* gamma,
                                                const float* W2, const float* b2, const float* OV,
                                                const float* pt, const float* divpart, void* dout) {
    __shared__ __attribute__((aligned(16)))
        float smem[2 * K_ * C_ + C_ + 8 + K_ * 256 + 20 * 512];
    if (*flag) fin_body<true >(feat, outb, gamma, W2, b2, OV, pt, divpart, dout, smem);
    else       fin_body<false>(feat, outb, gamma, W2, b2, OV, pt, divpart, dout, smem);
}

extern "C" void kernel_launch(void* const* d_in, const int* in_sizes, int n_in,
                              void* d_out, int out_size, void* d_ws, size_t ws_size,
                              hipStream_t stream) {
    const void* feat = d_in[0];
    const void* mask = d_in[1];
    const void* pq   = d_in[2];
    const void* temp = d_in[3];
    const void* marg = d_in[4];
    const void* qw   = d_in[5];
    const void* bnw  = d_in[6];
    const void* bnb  = d_in[7];
    const void* bnm  = d_in[8];
    const void* bnv  = d_in[9];
    const void* kw   = d_in[10];
    const void* kb   = d_in[11];
    const void* vw   = d_in[12];
    const void* vb   = d_in[13];
    const void* ow   = d_in[14];
    const void* ob   = d_in[15];
    const void* gm   = d_in[16];

    float* ws  = (float*)d_ws;
    float* ptp = ws;                               // B*NT*K*C = 655360
    float* mz  = ptp + (size_t)B_ * NT_ * K_ * C_; // B*NT*K*2 = 5120
    float* pt  = mz  + (size_t)B_ * NT_ * K_ * 2;  // 40960
    float* qn  = pt  + B_ * K_ * C_;               // 1280
    float* W2  = qn  + K_ * C_;                    // 40960
    float* b2  = W2  + B_ * K_ * C_;               // 160
    float* OV  = b2  + B_ * K_;                    // 40960
    float* dvp = OV  + B_ * K_ * C_;               // 32
    int*  flag = (int*)(dvp + B_);

    hipLaunchKernelGGL(k_init, dim3(1), dim3(256), 0, stream, feat, pq, qn, flag);
    hipLaunchKernelGGL(k_simpt, dim3(NT_, B_), dim3(512), 0, stream,
                       flag, feat, mask, temp, qn, ptp, mz);
    hipLaunchKernelGGL(k_merge, dim3(B_), dim3(256), 0, stream, ptp, mz, pt);
    hipLaunchKernelGGL(k_prepdiv, dim3(160 + B_), dim3(256), 0, stream,
                       flag, qw, kw, kb, vw, vb, ow, bnw, bnb, bnm, bnv, pt, marg,
                       W2, b2, OV, dvp);
    hipLaunchKernelGGL(k_fin, dim3(HW_ / 256, B_), dim3(512), 0, stream,
                       flag, feat, ob, gm, W2, b2, OV, pt, dvp, d_out);
}

// Round 5
// 176.375 us; speedup vs baseline: 1.6570x; 1.0551x over previous
//
#include <hip/hip_runtime.h>
#include <hip/hip_bf16.h>
#include <math.h>

#define B_  32
#define C_  256
#define HW_ 4096
#define K_  5
#define NT_ 16          // n-tiles per batch for k_simpt (256 positions each)

typedef __hip_bfloat16 bf16;

// ---------- dtype-flexible load/store ----------
template<bool BF>
__device__ inline float LD(const void* p, size_t i) {
    if (BF) return __bfloat162float(((const bf16*)p)[i]);
    return ((const float*)p)[i];
}
template<bool BF>
__device__ inline void ST(void* p, size_t i, float v) {
    if (BF) ((bf16*)p)[i] = __float2bfloat16(v);
    else    ((float*)p)[i] = v;
}
template<bool BF>
__device__ inline float4 LD4(const void* p, size_t i) {   // i: element index, %4==0
    if (BF) {
        ushort4 u = *(const ushort4*)((const unsigned short*)p + i);
        float4 r;
        r.x = __uint_as_float(((unsigned)u.x) << 16);
        r.y = __uint_as_float(((unsigned)u.y) << 16);
        r.z = __uint_as_float(((unsigned)u.z) << 16);
        r.w = __uint_as_float(((unsigned)u.w) << 16);
        return r;
    }
    return *(const float4*)((const float*)p + i);
}
template<bool BF>
__device__ inline float2 LD2(const void* p, size_t i) {   // i: element index, %2==0
    if (BF) {
        ushort2 u = *(const ushort2*)((const unsigned short*)p + i);
        return make_float2(__uint_as_float(((unsigned)u.x) << 16),
                           __uint_as_float(((unsigned)u.y) << 16));
    }
    return *(const float2*)((const float*)p + i);
}
template<bool BF>
__device__ inline void ST2(void* p, size_t i, float2 v) {
    if (BF) {
        bf16 a = __float2bfloat16(v.x), b = __float2bfloat16(v.y);
        ushort2 u;
        u.x = *(unsigned short*)&a; u.y = *(unsigned short*)&b;
        *(ushort2*)((unsigned short*)p + i) = u;
    } else {
        *(float2*)((float*)p + i) = v;
    }
}

// ---------- block reductions (256 threads = 4 waves) ----------
__device__ inline float blk_sum(float v, float* sh) {
    for (int o = 32; o > 0; o >>= 1) v += __shfl_down(v, o, 64);
    int w = threadIdx.x >> 6;
    __syncthreads();
    if ((threadIdx.x & 63) == 0) sh[w] = v;
    __syncthreads();
    return sh[0] + sh[1] + sh[2] + sh[3];
}

// ---------- 0: dtype detect + part_queries normalize (1 block, 256 thr) ----------
template<bool BF>
__device__ void qnorm_body(const void* pq, float* qn, float* sh) {
    int t = threadIdx.x;  // t == c
    for (int k = 0; k < K_; k++) {
        float v = LD<BF>(pq, (size_t)k * C_ + t);
        float ss = blk_sum(v * v, sh);
        float inv = 1.0f / fmaxf(sqrtf(ss), 1e-12f);
        qn[k * C_ + t] = v * inv;
    }
}
__global__ void k_init(const void* feat, const void* pq, float* qn, int* flag) {
    __shared__ int cnt;
    __shared__ int flg;
    __shared__ float sh[4];
    int t = threadIdx.x;
    if (t == 0) cnt = 0;
    __syncthreads();
    const unsigned short* u = (const unsigned short*)feat;
    int local = 0;
    for (int i = t; i < 4096; i += 256) {
        float v = __uint_as_float(((unsigned)u[i]) << 16);
        float a = fabsf(v);
        if (a >= 1e-4f && a <= 100.f) local++;
    }
    atomicAdd(&cnt, local);
    __syncthreads();
    if (t == 0) { flg = (cnt > 3072) ? 1 : 0; *flag = flg; }
    __syncthreads();
    if (flg) qnorm_body<true>(pq, qn, sh); else qnorm_body<false>(pq, qn, sh);
}

// ---------- 1: FUSED sim + block softmax partial + pt partial ----------
// 512 thr (8 waves), tile = 256 positions, wave = 32-channel slice.
// phase 2 reduce: 3-step 8-lane shfl partial -> LDS (stride 9) -> final sweep.
template<bool BF>
__device__ void simpt_body(const void* feat, const void* mask, const void* temp,
                           const float* qn, float* ptp, float* mz,
                           float* qL, float* red, float* wL) {
    int t = threadIdx.x;
    int lane = t & 63, q = t >> 6;
    int b = blockIdx.y, tile = blockIdx.x;
    int n0 = tile * 256 + lane * 4;
    for (int i = t; i < K_ * C_; i += 512) qL[i] = qn[i];
    __syncthreads();
    size_t base = (size_t)b * C_ * HW_ + n0;
    int c0 = q * 32;
    // phase 1: partial ss + dots over this wave's 32 channels
    float sa[4] = {0.f, 0.f, 0.f, 0.f};
    float da[K_][4];
    #pragma unroll
    for (int k = 0; k < K_; k++)
        #pragma unroll
        for (int i = 0; i < 4; i++) da[k][i] = 0.f;
    #pragma unroll 8
    for (int cc = 0; cc < 32; cc++) {
        int c = c0 + cc;
        float4 f = LD4<BF>(feat, base + (size_t)c * HW_);
        sa[0] += f.x * f.x; sa[1] += f.y * f.y; sa[2] += f.z * f.z; sa[3] += f.w * f.w;
        #pragma unroll
        for (int k = 0; k < K_; k++) {
            float qv = qL[k * C_ + c];
            da[k][0] += f.x * qv; da[k][1] += f.y * qv;
            da[k][2] += f.z * qv; da[k][3] += f.w * qv;
        }
    }
    #pragma unroll
    for (int i = 0; i < 4; i++) {
        red[(i * 6 + 0) * 512 + t] = sa[i];
        #pragma unroll
        for (int k = 0; k < K_; k++) red[(i * 6 + 1 + k) * 512 + t] = da[k][i];
    }
    __syncthreads();
    if (q < K_) {   // wave q: finalize sim row k=q for the 256 positions
        float tinv = 1.0f / fmaxf(LD<BF>(temp, 0), 0.01f);
        float4 m4 = LD4<BF>(mask, (size_t)b * HW_ + n0);
        float mv[4] = {m4.x, m4.y, m4.z, m4.w};
        float sv[4];
        #pragma unroll
        for (int i = 0; i < 4; i++) {
            float ssum = 0.f, dsum = 0.f;
            #pragma unroll
            for (int g = 0; g < 8; g++) {
                ssum += red[(i * 6 + 0) * 512 + g * 64 + lane];
                dsum += red[(i * 6 + 1 + q) * 512 + g * 64 + lane];
            }
            sv[i] = (mv[i] > 0.f) ? dsum * (tinv / fmaxf(sqrtf(ssum), 1e-12f))
                                  : -INFINITY;
        }
        float m = fmaxf(fmaxf(sv[0], sv[1]), fmaxf(sv[2], sv[3]));
        for (int o = 32; o > 0; o >>= 1) m = fmaxf(m, __shfl_xor(m, o, 64));
        float z = 0.f;
        #pragma unroll
        for (int i = 0; i < 4; i++) {
            float e = (sv[i] == -INFINITY) ? 0.f : __expf(sv[i] - m);
            wL[q * 256 + lane * 4 + i] = e;
            z += e;
        }
        for (int o = 32; o > 0; o >>= 1) z += __shfl_xor(z, o, 64);
        if (lane == 0) {
            size_t mzb = ((size_t)(b * NT_ + tile) * K_ + q) * 2;
            mz[mzb] = m; mz[mzb + 1] = z;
        }
    }
    __syncthreads();   // finalize done (red free), wL ready
    // phase 2: weighted accumulation over same 32 channels (feat L2-warm).
    float wv[K_][4];
    #pragma unroll
    for (int k = 0; k < K_; k++)
        #pragma unroll
        for (int i = 0; i < 4; i++) wv[k][i] = wL[k * 256 + lane * 4 + i];
    int g8 = lane >> 3;
    bool leader = (lane & 7) == 0;
    #pragma unroll 4
    for (int cc = 0; cc < 32; cc++) {
        int c = c0 + cc;
        float4 f = LD4<BF>(feat, base + (size_t)c * HW_);
        float p[K_];
        #pragma unroll
        for (int k = 0; k < K_; k++)
            p[k] = f.x * wv[k][0] + f.y * wv[k][1] + f.z * wv[k][2] + f.w * wv[k][3];
        #pragma unroll
        for (int k = 0; k < K_; k++) {
            float v = p[k];
            v += __shfl_down(v, 4, 8);
            v += __shfl_down(v, 2, 8);
            v += __shfl_down(v, 1, 8);
            p[k] = v;
        }
        if (leader) {
            #pragma unroll
            for (int k = 0; k < K_; k++) red[(c * K_ + k) * 9 + g8] = p[k];
        }
    }
    __syncthreads();
    // final sweep: 1280 outputs, 8 partials each
    size_t pb = ((size_t)(b * NT_ + tile) * K_) * C_;
    for (int o = t; o < C_ * K_; o += 512) {
        float s = 0.f;
        #pragma unroll
        for (int g = 0; g < 8; g++) s += red[o * 9 + g];
        int c = o / K_, k = o - c * K_;
        ptp[pb + (size_t)k * C_ + c] = s;
    }
}
__global__ __launch_bounds__(512, 4) void k_simpt(const int* flag, const void* feat,
                                                  const void* mask, const void* temp,
                                                  const float* qn, float* ptp, float* mz) {
    __shared__ __attribute__((aligned(16))) float qL[K_ * C_];
    __shared__ __attribute__((aligned(16))) float red[24 * 512];   // phase1 / phase2 union
    __shared__ __attribute__((aligned(16))) float wL[K_ * 256];
    if (*flag) simpt_body<true >(feat, mask, temp, qn, ptp, mz, qL, red, wL);
    else       simpt_body<false>(feat, mask, temp, qn, ptp, mz, qL, red, wL);
}

// ---------- 2: merge tile partials -> part_tokens ----------
__global__ void k_merge(const float* ptp, const float* mz, float* pt) {
    int b = blockIdx.x, t = threadIdx.x;   // t == c
    #pragma unroll
    for (int k = 0; k < K_; k++) {
        float M = -INFINITY;
        #pragma unroll
        for (int tl = 0; tl < NT_; tl++)
            M = fmaxf(M, mz[((size_t)(b * NT_ + tl) * K_ + k) * 2]);
        float Zs = 0.f, acc = 0.f;
        #pragma unroll
        for (int tl = 0; tl < NT_; tl++) {
            size_t mzb = ((size_t)(b * NT_ + tl) * K_ + k) * 2;
            float m_t = mz[mzb], z_t = mz[mzb + 1];
            float s = (m_t == -INFINITY) ? 0.f : __expf(m_t - M);
            Zs += z_t * s;
            acc += ptp[((size_t)(b * NT_ + tl) * K_ + k) * C_ + t] * s;
        }
        pt[((size_t)b * K_ + k) * C_ + t] = (Zs > 0.f) ? acc / Zs : 0.f;
    }
}

// ---------- 3: prep (W2, b2, OV per b,k) + diversity partials, merged grid ----------
template<bool BF>
__device__ void prep_body(const void* qw, const void* kw, const void* kb,
                          const void* vw, const void* vb, const void* ow,
                          const void* bnw, const void* bnb, const void* bnm, const void* bnv,
                          const float* pt, float* W2, float* b2, float* OV, float* smem) {
    float* ptL = smem;            // 256
    float* KtL = smem + 256;      // 256 (pre-scaled by bn scale)
    float* VtL = smem + 512;      // 256
    float* sh  = smem + 768;      // 4
    int bk = blockIdx.x, t = threadIdx.x;
    ptL[t] = pt[(size_t)bk * C_ + t];
    __syncthreads();
    float kt = LD<BF>(kb, t), vt = LD<BF>(vb, t);
    for (int c = 0; c < C_; c += 4) {
        float4 p4 = *(float4*)(ptL + c);
        float4 kw4 = LD4<BF>(kw, (size_t)t * C_ + c);
        float4 vw4 = LD4<BF>(vw, (size_t)t * C_ + c);
        kt += kw4.x * p4.x + kw4.y * p4.y + kw4.z * p4.z + kw4.w * p4.w;
        vt += vw4.x * p4.x + vw4.y * p4.y + vw4.z * p4.z + vw4.w * p4.w;
    }
    float scale = LD<BF>(bnw, t) * rsqrtf(LD<BF>(bnv, t) + 1e-5f);
    float shift = LD<BF>(bnb, t) - LD<BF>(bnm, t) * scale;
    KtL[t] = kt * scale;
    VtL[t] = vt;
    float bpart = kt * shift;
    __syncthreads();
    float ov = 0;
    for (int c = 0; c < C_; c += 4) {
        float4 v4 = *(float4*)(VtL + c);
        float4 ow4 = LD4<BF>(ow, (size_t)t * C_ + c);
        ov += ow4.x * v4.x + ow4.y * v4.y + ow4.z * v4.z + ow4.w * v4.w;
    }
    OV[(size_t)bk * C_ + t] = ov;
    float w2 = 0;
    for (int o = 0; o < C_; o++) w2 += KtL[o] * LD<BF>(qw, (size_t)o * C_ + t);
    W2[(size_t)bk * C_ + t] = w2 * (1.0f / 16.0f);
    float bs = blk_sum(bpart, sh);
    if (t == 0) b2[bk] = bs * (1.0f / 16.0f);
}
template<bool BF>
__device__ void div_body(const float* pt, const void* margin, float* divpart, float* smem) {
    float* ptL = smem;                 // 1280
    float* rn  = smem + K_ * C_;       // 5
    float* sh  = rn + 8;               // 4
    int b = blockIdx.x - 160, t = threadIdx.x;
    for (int i = t; i < K_ * C_; i += 256) ptL[i] = pt[(size_t)b * K_ * C_ + i];
    __syncthreads();
    for (int k = 0; k < K_; k++) {
        float v = ptL[k * C_ + t];
        float s = blk_sum(v * v, sh);
        if (t == 0) rn[k] = 1.0f / fmaxf(sqrtf(s), 1e-12f);
    }
    __syncthreads();
    float m = LD<BF>(margin, 0);
    m = fminf(fmaxf(m, 0.f), 0.5f);
    int p = t >> 3, g = t & 7;
    float contrib = 0.f;
    if (p < K_ * K_) {
        int k = p / K_, j = p % K_;
        float d = 0;
        for (int c = g; c < C_; c += 8) d += ptL[k * C_ + c] * ptL[j * C_ + c];
        d += __shfl_down(d, 4, 8);
        d += __shfl_down(d, 2, 8);
        d += __shfl_down(d, 1, 8);
        if (g == 0 && k != j) contrib = fmaxf(d * rn[k] * rn[j] - m, 0.f);
    }
    float s = blk_sum(contrib, sh);
    if (t == 0) divpart[b] = s;
}
__global__ void k_prepdiv(const int* flag, const void* qw, const void* kw, const void* kb,
                          const void* vw, const void* vb, const void* ow,
                          const void* bnw, const void* bnb, const void* bnm, const void* bnv,
                          const float* pt, const void* margin,
                          float* W2, float* b2, float* OV, float* divpart) {
    __shared__ __attribute__((aligned(16))) float smem[K_ * C_ + 16];
    if (blockIdx.x < 160) {
        if (*flag) prep_body<true >(qw, kw, kb, vw, vb, ow, bnw, bnb, bnm, bnv, pt, W2, b2, OV, smem);
        else       prep_body<false>(qw, kw, kb, vw, vb, ow, bnw, bnb, bnm, bnv, pt, W2, b2, OV, smem);
    } else {
        if (*flag) div_body<true >(pt, margin, divpart, smem);
        else       div_body<false>(pt, margin, divpart, smem);
    }
}

// ---------- 4: fused refine-attn + residual [tile=128, 256 thr, 4 waves x 64 ch] ----------
template<bool BF>
__device__ void fin_body(const void* feat, const void* outb, const void* gamma,
                         const float* W2, const float* b2, const float* OV,
                         const float* pt, const float* divpart,
                         void* dout, float* smem) {
    float* W2L = smem;                  // 1280
    float* OVL = W2L + K_ * C_;         // 1280
    float* obL = OVL + K_ * C_;         // 256
    float* b2L = obL + C_;              // 8
    float* eL  = b2L + 8;               // 5*128 = 640
    float* red = eL + K_ * 128;         // 10*256 = 2560
    int t = threadIdx.x, lane = t & 63, w = t >> 6;
    int b = blockIdx.y;
    int n0 = blockIdx.x * 128 + lane * 2;
    for (int i = t; i < K_ * C_; i += 256) {
        W2L[i] = W2[(size_t)b * K_ * C_ + i];
        OVL[i] = OV[(size_t)b * K_ * C_ + i];
    }
    obL[t] = LD<BF>(outb, t);
    if (t < K_) b2L[t] = b2[b * K_ + t];
    __syncthreads();
    size_t base = (size_t)b * C_ * HW_ + n0;
    int c0 = w * 64;
    // phase 1: partial logits over this wave's 64 channels
    float la[K_][2];
    #pragma unroll
    for (int k = 0; k < K_; k++) { la[k][0] = 0.f; la[k][1] = 0.f; }
    #pragma unroll 8
    for (int cc = 0; cc < 64; cc++) {
        int c = c0 + cc;
        float2 f = LD2<BF>(feat, base + (size_t)c * HW_);
        #pragma unroll
        for (int k = 0; k < K_; k++) {
            float wv = W2L[k * C_ + c];
            la[k][0] += f.x * wv; la[k][1] += f.y * wv;
        }
    }
    #pragma unroll
    for (int i = 0; i < 2; i++)
        #pragma unroll
        for (int k = 0; k < K_; k++) red[(i * K_ + k) * 256 + t] = la[k][i];
    __syncthreads();
    // finalize: thread p<128 owns in-tile position p = L*2+i
    if (t < 128) {
        int i = t & 1, L = t >> 1;
        float lg[K_];
        #pragma unroll
        for (int k = 0; k < K_; k++) {
            float s = b2L[k];
            #pragma unroll
            for (int g = 0; g < 4; g++) s += red[(i * K_ + k) * 256 + g * 64 + L];
            lg[k] = s;
        }
        float mx = fmaxf(fmaxf(fmaxf(lg[0], lg[1]), fmaxf(lg[2], lg[3])), lg[4]);
        float e0 = __expf(lg[0] - mx), e1 = __expf(lg[1] - mx), e2 = __expf(lg[2] - mx),
              e3 = __expf(lg[3] - mx), e4 = __expf(lg[4] - mx);
        float inv = 1.0f / (e0 + e1 + e2 + e3 + e4);
        eL[0 * 128 + t] = e0 * inv; eL[1 * 128 + t] = e1 * inv;
        eL[2 * 128 + t] = e2 * inv; eL[3 * 128 + t] = e3 * inv;
        eL[4 * 128 + t] = e4 * inv;
    }
    __syncthreads();
    float e[K_][2];
    #pragma unroll
    for (int k = 0; k < K_; k++) {
        e[k][0] = eL[k * 128 + lane * 2];
        e[k][1] = eL[k * 128 + lane * 2 + 1];
    }
    float g = LD<BF>(gamma, 0);
    // phase 2: output over this wave's 64 channels (feat L2-warm)
    #pragma unroll 8
    for (int oo = 0; oo < 64; oo++) {
        int o = c0 + oo;
        float2 f = LD2<BF>(feat, base + (size_t)o * HW_);
        float ob = obL[o];
        float ax = ob, ay = ob;
        #pragma unroll
        for (int k = 0; k < K_; k++) {
            float ovv = OVL[k * C_ + o];
            ax += e[k][0] * ovv; ay += e[k][1] * ovv;
        }
        f.x += g * ax; f.y += g * ay;
        ST2<BF>(dout, base + (size_t)o * HW_, f);
    }
    // aux outputs: part_tokens + div_loss (b==0 slice: 32 blocks x 256 thr)
    if (b == 0) {
        const size_t enh = (size_t)B_ * C_ * HW_;
        for (int i = blockIdx.x * 256 + t; i < B_ * K_ * C_; i += 32 * 256)
            ST<BF>(dout, enh + 1 + i, pt[i]);
        if (blockIdx.x == 0 && t == 0) {
            float s = 0;
            for (int bb = 0; bb < B_; bb++) s += divpart[bb];
            ST<BF>(dout, enh, s / (640.0f + 1e-5f));
        }
    }
}
__global__ __launch_bounds__(256, 4) void k_fin(const int* flag, const void* feat,
                                                const void* outb, const void* gamma,
                                                const float* W2, const float* b2, const float* OV,
                                                const float* pt, const float* divpart, void* dout) {
    __shared__ __attribute__((aligned(16)))
        float smem[2 * K_ * C_ + C_ + 8 + K_ * 128 + 10 * 256];
    if (*flag) fin_body<true >(feat, outb, gamma, W2, b2, OV, pt, divpart, dout, smem);
    else       fin_body<false>(feat, outb, gamma, W2, b2, OV, pt, divpart, dout, smem);
}

extern "C" void kernel_launch(void* const* d_in, const int* in_sizes, int n_in,
                              void* d_out, int out_size, void* d_ws, size_t ws_size,
                              hipStream_t stream) {
    const void* feat = d_in[0];
    const void* mask = d_in[1];
    const void* pq   = d_in[2];
    const void* temp = d_in[3];
    const void* marg = d_in[4];
    const void* qw   = d_in[5];
    const void* bnw  = d_in[6];
    const void* bnb  = d_in[7];
    const void* bnm  = d_in[8];
    const void* bnv  = d_in[9];
    const void* kw   = d_in[10];
    const void* kb   = d_in[11];
    const void* vw   = d_in[12];
    const void* vb   = d_in[13];
    const void* ow   = d_in[14];
    const void* ob   = d_in[15];
    const void* gm   = d_in[16];

    float* ws  = (float*)d_ws;
    float* ptp = ws;                               // B*NT*K*C = 655360
    float* mz  = ptp + (size_t)B_ * NT_ * K_ * C_; // B*NT*K*2 = 5120
    float* pt  = mz  + (size_t)B_ * NT_ * K_ * 2;  // 40960
    float* qn  = pt  + B_ * K_ * C_;               // 1280
    float* W2  = qn  + K_ * C_;                    // 40960
    float* b2  = W2  + B_ * K_ * C_;               // 160
    float* OV  = b2  + B_ * K_;                    // 40960
    float* dvp = OV  + B_ * K_ * C_;               // 32
    int*  flag = (int*)(dvp + B_);

    hipLaunchKernelGGL(k_init, dim3(1), dim3(256), 0, stream, feat, pq, qn, flag);
    hipLaunchKernelGGL(k_simpt, dim3(NT_, B_), dim3(512), 0, stream,
                       flag, feat, mask, temp, qn, ptp, mz);
    hipLaunchKernelGGL(k_merge, dim3(B_), dim3(256), 0, stream, ptp, mz, pt);
    hipLaunchKernelGGL(k_prepdiv, dim3(160 + B_), dim3(256), 0, stream,
                       flag, qw, kw, kb, vw, vb, ow, bnw, bnb, bnm, bnv, pt, marg,
                       W2, b2, OV, dvp);
    hipLaunchKernelGGL(k_fin, dim3(HW_ / 128, B_), dim3(256), 0, stream,
                       flag, feat, ob, gm, W2, b2, OV, pt, dvp, d_out);
}

// Round 6
// 167.421 us; speedup vs baseline: 1.7456x; 1.0535x over previous
//
#include <hip/hip_runtime.h>
#include <hip/hip_bf16.h>
#include <math.h>

#define B_  32
#define C_  256
#define HW_ 4096
#define K_  5
#define NT_ 16          // n-tiles per batch (256 positions each)

typedef __hip_bfloat16 bf16;
typedef unsigned int u32;

// ---------- dtype-flexible load/store ----------
template<bool BF>
__device__ inline float LD(const void* p, size_t i) {
    if (BF) return __bfloat162float(((const bf16*)p)[i]);
    return ((const float*)p)[i];
}
template<bool BF>
__device__ inline void ST(void* p, size_t i, float v) {
    if (BF) ((bf16*)p)[i] = __float2bfloat16(v);
    else    ((float*)p)[i] = v;
}
template<bool BF>
__device__ inline float4 LD4(const void* p, size_t i) {   // i: element index, %4==0
    if (BF) {
        ushort4 u = *(const ushort4*)((const unsigned short*)p + i);
        float4 r;
        r.x = __uint_as_float(((u32)u.x) << 16);
        r.y = __uint_as_float(((u32)u.y) << 16);
        r.z = __uint_as_float(((u32)u.z) << 16);
        r.w = __uint_as_float(((u32)u.w) << 16);
        return r;
    }
    return *(const float4*)((const float*)p + i);
}
template<bool BF>
__device__ inline void ST4(void* p, size_t i, float4 v) {
    if (BF) {
        bf16 a = __float2bfloat16(v.x), b = __float2bfloat16(v.y),
             c = __float2bfloat16(v.z), d = __float2bfloat16(v.w);
        ushort4 u;
        u.x = *(unsigned short*)&a; u.y = *(unsigned short*)&b;
        u.z = *(unsigned short*)&c; u.w = *(unsigned short*)&d;
        *(ushort4*)((unsigned short*)p + i) = u;
    } else {
        *(float4*)((float*)p + i) = v;
    }
}

__device__ inline u32 packbf2(float a, float b) {   // a -> low 16 (even pos)
    bf16 x = __float2bfloat16(a), y = __float2bfloat16(b);
    return (((u32)*(unsigned short*)&y) << 16) | (u32)(*(unsigned short*)&x);
}
__device__ inline float lo16f(u32 u) { return __uint_as_float(u << 16); }
__device__ inline float hi16f(u32 u) { return __uint_as_float(u & 0xffff0000u); }

// ---------- block reductions (256 threads = 4 waves) ----------
__device__ inline float blk_sum(float v, float* sh) {
    for (int o = 32; o > 0; o >>= 1) v += __shfl_down(v, o, 64);
    int w = threadIdx.x >> 6;
    __syncthreads();
    if ((threadIdx.x & 63) == 0) sh[w] = v;
    __syncthreads();
    return sh[0] + sh[1] + sh[2] + sh[3];
}

// ---------- 0: dtype detect + part_queries normalize (1 block, 256 thr) ----------
template<bool BF>
__device__ void qnorm_body(const void* pq, float* qn, float* sh) {
    int t = threadIdx.x;  // t == c
    for (int k = 0; k < K_; k++) {
        float v = LD<BF>(pq, (size_t)k * C_ + t);
        float ss = blk_sum(v * v, sh);
        float inv = 1.0f / fmaxf(sqrtf(ss), 1e-12f);
        qn[k * C_ + t] = v * inv;
    }
}
__global__ void k_init(const void* feat, const void* pq, float* qn, int* flag) {
    __shared__ int cnt;
    __shared__ int flg;
    __shared__ float sh[4];
    int t = threadIdx.x;
    if (t == 0) cnt = 0;
    __syncthreads();
    const unsigned short* u = (const unsigned short*)feat;
    int local = 0;
    for (int i = t; i < 4096; i += 256) {
        float v = __uint_as_float(((u32)u[i]) << 16);
        float a = fabsf(v);
        if (a >= 1e-4f && a <= 100.f) local++;
    }
    atomicAdd(&cnt, local);
    __syncthreads();
    if (t == 0) { flg = (cnt > 3072) ? 1 : 0; *flag = flg; }
    __syncthreads();
    if (flg) qnorm_body<true>(pq, qn, sh); else qnorm_body<false>(pq, qn, sh);
}

// ---------- 1: FUSED sim + softmax partial + pt partial, bf16 LDS-staged tile ----------
// 512 thr (8 waves x 32ch), tile = 256 positions. Phase 1: coalesced float4 feat
// reads -> dots in regs + bf16 tile staged to LDS (XOR-swizzled words).
// Finalize in 2 rounds (red = 24KB reused). Phase 2: channel-owner, pure LDS,
// NO shuffles, NO global re-read.
template<bool BF>
__device__ void simpt_body(const void* feat, const void* mask, const void* temp,
                           const float* qn, float* ptp, float* mz, float* smem) {
    u32*   featU = (u32*)smem;            // 32768 u32 = 128 KB, [c][128 words] swizzled
    float* red   = smem + 32768;          // 6144 f32 = 24 KB (rounds; later wL/psum)
    float* wL    = red;                   // 1280 (alias after finalize)
    float* psum  = red + 1280;            // 2560 (alias)
    float* qL    = smem + 32768 + 6144;   // 1280
    int t = threadIdx.x, lane = t & 63, q = t >> 6;
    int b = blockIdx.y, tile = blockIdx.x;
    int n0 = tile * 256 + lane * 4;
    for (int i = t; i < K_ * C_; i += 512) qL[i] = qn[i];
    __syncthreads();
    size_t base = (size_t)b * C_ * HW_ + n0;
    int c0 = q * 32;
    // ---- phase 1 ----
    float sa[4] = {0.f, 0.f, 0.f, 0.f};
    float da[K_][4];
    #pragma unroll
    for (int k = 0; k < K_; k++)
        #pragma unroll
        for (int i = 0; i < 4; i++) da[k][i] = 0.f;
    #pragma unroll 8
    for (int cc = 0; cc < 32; cc++) {
        int c = c0 + cc;
        float4 f = LD4<BF>(feat, base + (size_t)c * HW_);
        sa[0] += f.x * f.x; sa[1] += f.y * f.y; sa[2] += f.z * f.z; sa[3] += f.w * f.w;
        #pragma unroll
        for (int k = 0; k < K_; k++) {
            float qv = qL[k * C_ + c];
            da[k][0] += f.x * qv; da[k][1] += f.y * qv;
            da[k][2] += f.z * qv; da[k][3] += f.w * qv;
        }
        // stage bf16 tile, word-swizzled: word w of row c stored at w^(c&31)
        u32 w01 = packbf2(f.x, f.y), w23 = packbf2(f.z, f.w);
        int x = c & 31;
        int wb = ((lane * 2) ^ x) & ~1;
        uint2 val = (x & 1) ? make_uint2(w23, w01) : make_uint2(w01, w23);
        *(uint2*)(featU + c * 128 + wb) = val;
    }
    // ---- finalize: 2 rounds over position-pairs ----
    float sv[4];
    float tinv = 0.f;
    float mvarr[4] = {0.f, 0.f, 0.f, 0.f};
    if (q < K_) {
        tinv = 1.0f / fmaxf(LD<BF>(temp, 0), 0.01f);
        float4 m4 = LD4<BF>(mask, (size_t)b * HW_ + n0);
        mvarr[0] = m4.x; mvarr[1] = m4.y; mvarr[2] = m4.z; mvarr[3] = m4.w;
    }
    for (int r = 0; r < 2; r++) {
        #pragma unroll
        for (int di = 0; di < 2; di++) {
            int i = 2 * r + di;
            red[(di * 6 + 0) * 512 + t] = sa[i];
            #pragma unroll
            for (int k = 0; k < K_; k++) red[(di * 6 + 1 + k) * 512 + t] = da[k][i];
        }
        __syncthreads();
        if (q < K_) {
            #pragma unroll
            for (int di = 0; di < 2; di++) {
                int i = 2 * r + di;
                float ssum = 0.f, dsum = 0.f;
                #pragma unroll
                for (int g = 0; g < 8; g++) {
                    ssum += red[(di * 6 + 0) * 512 + g * 64 + lane];
                    dsum += red[(di * 6 + 1 + q) * 512 + g * 64 + lane];
                }
                sv[i] = (mvarr[i] > 0.f) ? dsum * (tinv / fmaxf(sqrtf(ssum), 1e-12f))
                                         : -INFINITY;
            }
        }
        __syncthreads();
    }
    // wave-softmax partial (m, z) and weights -> wL (red is dead now)
    if (q < K_) {
        float m = fmaxf(fmaxf(sv[0], sv[1]), fmaxf(sv[2], sv[3]));
        for (int o = 32; o > 0; o >>= 1) m = fmaxf(m, __shfl_xor(m, o, 64));
        float ev[4];
        float z = 0.f;
        #pragma unroll
        for (int i = 0; i < 4; i++) {
            ev[i] = (sv[i] == -INFINITY) ? 0.f : __expf(sv[i] - m);
            z += ev[i];
        }
        for (int o = 32; o > 0; o >>= 1) z += __shfl_xor(z, o, 64);
        *(float4*)(wL + q * 256 + lane * 4) = make_float4(ev[0], ev[1], ev[2], ev[3]);
        if (lane == 0) {
            size_t mzb = ((size_t)(b * NT_ + tile) * K_ + q) * 2;
            mz[mzb] = m; mz[mzb + 1] = z;
        }
    }
    __syncthreads();
    // ---- phase 2: channel-owner accumulation from LDS tile ----
    int c = t & 255, h = t >> 8, x = c & 31;
    const u32* frow = featU + c * 128;
    float acc[K_] = {0.f, 0.f, 0.f, 0.f, 0.f};
    #pragma unroll 4
    for (int j = 0; j < 32; j++) {
        int w = h * 64 + j * 2;
        int wb = (w ^ x) & ~1;
        uint2 v = *(const uint2*)(frow + wb);
        u32 a0 = (x & 1) ? v.y : v.x;   // word w   (pos 2w, 2w+1)
        u32 a1 = (x & 1) ? v.x : v.y;   // word w+1 (pos 2w+2, 2w+3)
        float f0 = lo16f(a0), f1 = hi16f(a0), f2 = lo16f(a1), f3 = hi16f(a1);
        int n = 2 * w;
        #pragma unroll
        for (int k = 0; k < K_; k++) {
            float4 w4 = *(const float4*)(wL + k * 256 + n);
            acc[k] += f0 * w4.x + f1 * w4.y + f2 * w4.z + f3 * w4.w;
        }
    }
    #pragma unroll
    for (int k = 0; k < K_; k++) psum[h * 1280 + k * 256 + c] = acc[k];
    __syncthreads();
    size_t pb = ((size_t)(b * NT_ + tile) * K_) * C_;
    for (int o = t; o < K_ * C_; o += 512)
        ptp[pb + o] = psum[o] + psum[1280 + o];
}
__global__ __launch_bounds__(512, 2) void k_simpt(const int* flag, const void* feat,
                                                  const void* mask, const void* temp,
                                                  const float* qn, float* ptp, float* mz) {
    __shared__ __attribute__((aligned(16))) float smem[40192];   // 160,768 B
    if (*flag) simpt_body<true >(feat, mask, temp, qn, ptp, mz, smem);
    else       simpt_body<false>(feat, mask, temp, qn, ptp, mz, smem);
}

// ---------- 2: merge tile partials -> part_tokens ----------
__global__ void k_merge(const float* ptp, const float* mz, float* pt) {
    int b = blockIdx.x, t = threadIdx.x;   // t == c
    #pragma unroll
    for (int k = 0; k < K_; k++) {
        float M = -INFINITY;
        #pragma unroll
        for (int tl = 0; tl < NT_; tl++)
            M = fmaxf(M, mz[((size_t)(b * NT_ + tl) * K_ + k) * 2]);
        float Zs = 0.f, acc = 0.f;
        #pragma unroll
        for (int tl = 0; tl < NT_; tl++) {
            size_t mzb = ((size_t)(b * NT_ + tl) * K_ + k) * 2;
            float m_t = mz[mzb], z_t = mz[mzb + 1];
            float s = (m_t == -INFINITY) ? 0.f : __expf(m_t - M);
            Zs += z_t * s;
            acc += ptp[((size_t)(b * NT_ + tl) * K_ + k) * C_ + t] * s;
        }
        pt[((size_t)b * K_ + k) * C_ + t] = (Zs > 0.f) ? acc / Zs : 0.f;
    }
}

// ---------- 3: prep (W2, b2, OV per b,k) + diversity partials, merged grid ----------
template<bool BF>
__device__ void prep_body(const void* qw, const void* kw, const void* kb,
                          const void* vw, const void* vb, const void* ow,
                          const void* bnw, const void* bnb, const void* bnm, const void* bnv,
                          const float* pt, float* W2, float* b2, float* OV, float* smem) {
    float* ptL = smem;            // 256
    float* KtL = smem + 256;      // 256 (pre-scaled by bn scale)
    float* VtL = smem + 512;      // 256
    float* sh  = smem + 768;      // 4
    int bk = blockIdx.x, t = threadIdx.x;
    ptL[t] = pt[(size_t)bk * C_ + t];
    __syncthreads();
    float kt = LD<BF>(kb, t), vt = LD<BF>(vb, t);
    for (int c = 0; c < C_; c += 4) {
        float4 p4 = *(float4*)(ptL + c);
        float4 kw4 = LD4<BF>(kw, (size_t)t * C_ + c);
        float4 vw4 = LD4<BF>(vw, (size_t)t * C_ + c);
        kt += kw4.x * p4.x + kw4.y * p4.y + kw4.z * p4.z + kw4.w * p4.w;
        vt += vw4.x * p4.x + vw4.y * p4.y + vw4.z * p4.z + vw4.w * p4.w;
    }
    float scale = LD<BF>(bnw, t) * rsqrtf(LD<BF>(bnv, t) + 1e-5f);
    float shift = LD<BF>(bnb, t) - LD<BF>(bnm, t) * scale;
    KtL[t] = kt * scale;
    VtL[t] = vt;
    float bpart = kt * shift;
    __syncthreads();
    float ov = 0;
    for (int c = 0; c < C_; c += 4) {
        float4 v4 = *(float4*)(VtL + c);
        float4 ow4 = LD4<BF>(ow, (size_t)t * C_ + c);
        ov += ow4.x * v4.x + ow4.y * v4.y + ow4.z * v4.z + ow4.w * v4.w;
    }
    OV[(size_t)bk * C_ + t] = ov;
    float w2 = 0;
    for (int o = 0; o < C_; o++) w2 += KtL[o] * LD<BF>(qw, (size_t)o * C_ + t);
    W2[(size_t)bk * C_ + t] = w2 * (1.0f / 16.0f);
    float bs = blk_sum(bpart, sh);
    if (t == 0) b2[bk] = bs * (1.0f / 16.0f);
}
template<bool BF>
__device__ void div_body(const float* pt, const void* margin, float* divpart, float* smem) {
    float* ptL = smem;                 // 1280
    float* rn  = smem + K_ * C_;       // 5
    float* sh  = rn + 8;               // 4
    int b = blockIdx.x - 160, t = threadIdx.x;
    for (int i = t; i < K_ * C_; i += 256) ptL[i] = pt[(size_t)b * K_ * C_ + i];
    __syncthreads();
    for (int k = 0; k < K_; k++) {
        float v = ptL[k * C_ + t];
        float s = blk_sum(v * v, sh);
        if (t == 0) rn[k] = 1.0f / fmaxf(sqrtf(s), 1e-12f);
    }
    __syncthreads();
    float m = LD<BF>(margin, 0);
    m = fminf(fmaxf(m, 0.f), 0.5f);
    int p = t >> 3, g = t & 7;
    float contrib = 0.f;
    if (p < K_ * K_) {
        int k = p / K_, j = p % K_;
        float d = 0;
        for (int c = g; c < C_; c += 8) d += ptL[k * C_ + c] * ptL[j * C_ + c];
        d += __shfl_down(d, 4, 8);
        d += __shfl_down(d, 2, 8);
        d += __shfl_down(d, 1, 8);
        if (g == 0 && k != j) contrib = fmaxf(d * rn[k] * rn[j] - m, 0.f);
    }
    float s = blk_sum(contrib, sh);
    if (t == 0) divpart[b] = s;
}
__global__ void k_prepdiv(const int* flag, const void* qw, const void* kw, const void* kb,
                          const void* vw, const void* vb, const void* ow,
                          const void* bnw, const void* bnb, const void* bnm, const void* bnv,
                          const float* pt, const void* margin,
                          float* W2, float* b2, float* OV, float* divpart) {
    __shared__ __attribute__((aligned(16))) float smem[K_ * C_ + 16];
    if (blockIdx.x < 160) {
        if (*flag) prep_body<true >(qw, kw, kb, vw, vb, ow, bnw, bnb, bnm, bnv, pt, W2, b2, OV, smem);
        else       prep_body<false>(qw, kw, kb, vw, vb, ow, bnw, bnb, bnm, bnv, pt, W2, b2, OV, smem);
    } else {
        if (*flag) div_body<true >(pt, margin, divpart, smem);
        else       div_body<false>(pt, margin, divpart, smem);
    }
}

// ---------- 4: fused refine-attn + residual, bf16 LDS-staged tile ----------
// 512 thr (8 waves x 32ch), tile = 256 positions. Phase 1: f32 dots + bf16 tile
// staging (plain [c][pos] layout: row-wise r/w, no swizzle needed).
// 2-round finalize -> per-position softmax e. Phase 2: pure LDS + coalesced store.
template<bool BF>
__device__ void fin_body(const void* feat, const void* outb, const void* gamma,
                         const float* W2, const float* b2, const float* OV,
                         const float* pt, const float* divpart,
                         void* dout, float* smem) {
    u32*   featU = (u32*)smem;                   // 32768 u32 = 128 KB
    float* red   = smem + 32768;                 // 5120 f32 = 20 KB
    float* W2L   = smem + 32768 + 5120;          // 1280 (ph1 only)
    float* eL    = W2L;                          // alias (finalize+ph2)
    float* OVL   = W2L + 1280;                   // 1280
    float* obL   = OVL + 1280;                   // 256
    float* b2L   = obL + 256;                    // 8
    int t = threadIdx.x, lane = t & 63, q = t >> 6;
    int b = blockIdx.y;
    int n0 = blockIdx.x * 256 + lane * 4;
    for (int i = t; i < K_ * C_; i += 512) {
        W2L[i] = W2[(size_t)b * K_ * C_ + i];
        OVL[i] = OV[(size_t)b * K_ * C_ + i];
    }
    for (int i = t; i < C_; i += 512) obL[i] = LD<BF>(outb, i);
    if (t < K_) b2L[t] = b2[b * K_ + t];
    __syncthreads();
    size_t base = (size_t)b * C_ * HW_ + n0;
    int c0 = q * 32;
    // ---- phase 1: logit partial dots + staging ----
    float la[K_][4];
    #pragma unroll
    for (int k = 0; k < K_; k++)
        #pragma unroll
        for (int i = 0; i < 4; i++) la[k][i] = 0.f;
    #pragma unroll 8
    for (int cc = 0; cc < 32; cc++) {
        int c = c0 + cc;
        float4 f = LD4<BF>(feat, base + (size_t)c * HW_);
        #pragma unroll
        for (int k = 0; k < K_; k++) {
            float wv = W2L[k * C_ + c];
            la[k][0] += f.x * wv; la[k][1] += f.y * wv;
            la[k][2] += f.z * wv; la[k][3] += f.w * wv;
        }
        *(uint2*)(featU + c * 128 + lane * 2) =
            make_uint2(packbf2(f.x, f.y), packbf2(f.z, f.w));
    }
    // ---- finalize: 2 rounds; per-position softmax (K-local) ----
    for (int r = 0; r < 2; r++) {
        #pragma unroll
        for (int di = 0; di < 2; di++) {
            int i = 2 * r + di;
            #pragma unroll
            for (int k = 0; k < K_; k++) red[(di * 5 + k) * 512 + t] = la[k][i];
        }
        __syncthreads();
        if (t < 128) {
            int L = t & 63, di = t >> 6;
            int n = L * 4 + 2 * r + di;
            float lg[K_];
            #pragma unroll
            for (int k = 0; k < K_; k++) {
                float s = b2L[k];
                #pragma unroll
                for (int g = 0; g < 8; g++) s += red[(di * 5 + k) * 512 + g * 64 + L];
                lg[k] = s;
            }
            float mx = fmaxf(fmaxf(fmaxf(lg[0], lg[1]), fmaxf(lg[2], lg[3])), lg[4]);
            float e0 = __expf(lg[0] - mx), e1 = __expf(lg[1] - mx), e2 = __expf(lg[2] - mx),
                  e3 = __expf(lg[3] - mx), e4 = __expf(lg[4] - mx);
            float inv = 1.0f / (e0 + e1 + e2 + e3 + e4);
            eL[0 * 256 + n] = e0 * inv; eL[1 * 256 + n] = e1 * inv;
            eL[2 * 256 + n] = e2 * inv; eL[3 * 256 + n] = e3 * inv;
            eL[4 * 256 + n] = e4 * inv;
        }
        __syncthreads();
    }
    // ---- phase 2: output from LDS tile, coalesced float4 stores ----
    float4 e4[K_];
    #pragma unroll
    for (int k = 0; k < K_; k++) e4[k] = *(const float4*)(eL + k * 256 + lane * 4);
    float g = LD<BF>(gamma, 0);
    #pragma unroll 4
    for (int cc = 0; cc < 32; cc++) {
        int c = c0 + cc;
        uint2 v = *(const uint2*)(featU + c * 128 + lane * 2);
        float f0 = lo16f(v.x), f1 = hi16f(v.x), f2 = lo16f(v.y), f3 = hi16f(v.y);
        float ob = obL[c];
        float a0 = ob, a1 = ob, a2 = ob, a3 = ob;
        #pragma unroll
        for (int k = 0; k < K_; k++) {
            float ov = OVL[k * C_ + c];
            a0 += e4[k].x * ov; a1 += e4[k].y * ov;
            a2 += e4[k].z * ov; a3 += e4[k].w * ov;
        }
        ST4<BF>(dout, base + (size_t)c * HW_,
                make_float4(f0 + g * a0, f1 + g * a1, f2 + g * a2, f3 + g * a3));
    }
    // aux outputs: part_tokens + div_loss (b==0 slice: 16 blocks x 512 thr)
    if (b == 0) {
        const size_t enh = (size_t)B_ * C_ * HW_;
        for (int i = blockIdx.x * 512 + t; i < B_ * K_ * C_; i += 16 * 512)
            ST<BF>(dout, enh + 1 + i, pt[i]);
        if (blockIdx.x == 0 && t == 0) {
            float s = 0;
            for (int bb = 0; bb < B_; bb++) s += divpart[bb];
            ST<BF>(dout, enh, s / (640.0f + 1e-5f));
        }
    }
}
__global__ __launch_bounds__(512, 2) void k_fin(const int* flag, const void* feat,
                                                const void* outb, const void* gamma,
                                                const float* W2, const float* b2, const float* OV,
                                                const float* pt, const float* divpart, void* dout) {
    __shared__ __attribute__((aligned(16))) float smem[40712];   // 162,848 B
    if (*flag) fin_body<true >(feat, outb, gamma, W2, b2, OV, pt, divpart, dout, smem);
    else       fin_body<false>(feat, outb, gamma, W2, b2, OV, pt, divpart, dout, smem);
}

extern "C" void kernel_launch(void* const* d_in, const int* in_sizes, int n_in,
                              void* d_out, int out_size, void* d_ws, size_t ws_size,
                              hipStream_t stream) {
    const void* feat = d_in[0];
    const void* mask = d_in[1];
    const void* pq   = d_in[2];
    const void* temp = d_in[3];
    const void* marg = d_in[4];
    const void* qw   = d_in[5];
    const void* bnw  = d_in[6];
    const void* bnb  = d_in[7];
    const void* bnm  = d_in[8];
    const void* bnv  = d_in[9];
    const void* kw   = d_in[10];
    const void* kb   = d_in[11];
    const void* vw   = d_in[12];
    const void* vb   = d_in[13];
    const void* ow   = d_in[14];
    const void* ob   = d_in[15];
    const void* gm   = d_in[16];

    float* ws  = (float*)d_ws;
    float* ptp = ws;                               // B*NT*K*C = 655360
    float* mz  = ptp + (size_t)B_ * NT_ * K_ * C_; // B*NT*K*2 = 5120
    float* pt  = mz  + (size_t)B_ * NT_ * K_ * 2;  // 40960
    float* qn  = pt  + B_ * K_ * C_;               // 1280
    float* W2  = qn  + K_ * C_;                    // 40960
    float* b2  = W2  + B_ * K_ * C_;               // 160
    float* OV  = b2  + B_ * K_;                    // 40960
    float* dvp = OV  + B_ * K_ * C_;               // 32
    int*  flag = (int*)(dvp + B_);

    hipLaunchKernelGGL(k_init, dim3(1), dim3(256), 0, stream, feat, pq, qn, flag);
    hipLaunchKernelGGL(k_simpt, dim3(NT_, B_), dim3(512), 0, stream,
                       flag, feat, mask, temp, qn, ptp, mz);
    hipLaunchKernelGGL(k_merge, dim3(B_), dim3(256), 0, stream, ptp, mz, pt);
    hipLaunchKernelGGL(k_prepdiv, dim3(160 + B_), dim3(256), 0, stream,
                       flag, qw, kw, kb, vw, vb, ow, bnw, bnb, bnm, bnv, pt, marg,
                       W2, b2, OV, dvp);
    hipLaunchKernelGGL(k_fin, dim3(HW_ / 256, B_), dim3(512), 0, stream,
                       flag, feat, ob, gm, W2, b2, OV, pt, dvp, d_out);
}

// Round 7
// 161.709 us; speedup vs baseline: 1.8073x; 1.0353x over previous
//
#include <hip/hip_runtime.h>
#include <hip/hip_bf16.h>
#include <math.h>

#define B_  32
#define C_  256
#define HW_ 4096
#define K_  5
#define P_  128          // positions per tile
#define NT_ 32           // HW_/P_

typedef __hip_bfloat16 bf16;
typedef unsigned int u32;

// ---------- dtype-flexible load/store ----------
template<bool BF>
__device__ inline float LD(const void* p, size_t i) {
    if (BF) return __bfloat162float(((const bf16*)p)[i]);
    return ((const float*)p)[i];
}
template<bool BF>
__device__ inline void ST(void* p, size_t i, float v) {
    if (BF) ((bf16*)p)[i] = __float2bfloat16(v);
    else    ((float*)p)[i] = v;
}
template<bool BF>
__device__ inline float4 LD4(const void* p, size_t i) {
    if (BF) {
        ushort4 u = *(const ushort4*)((const unsigned short*)p + i);
        float4 r;
        r.x = __uint_as_float(((u32)u.x) << 16);
        r.y = __uint_as_float(((u32)u.y) << 16);
        r.z = __uint_as_float(((u32)u.z) << 16);
        r.w = __uint_as_float(((u32)u.w) << 16);
        return r;
    }
    return *(const float4*)((const float*)p + i);
}
template<bool BF>
__device__ inline void ST2(void* p, size_t i, float2 v) {
    if (BF) {
        bf16 a = __float2bfloat16(v.x), b = __float2bfloat16(v.y);
        ushort2 u;
        u.x = *(unsigned short*)&a; u.y = *(unsigned short*)&b;
        *(ushort2*)((unsigned short*)p + i) = u;
    } else {
        *(float2*)((float*)p + i) = v;
    }
}
__device__ inline u32 packbf2(float a, float b) {   // a -> low 16
    bf16 x = __float2bfloat16(a), y = __float2bfloat16(b);
    return (((u32)*(unsigned short*)&y) << 16) | (u32)(*(unsigned short*)&x);
}
__device__ inline float lo16f(u32 u) { return __uint_as_float(u << 16); }
__device__ inline float hi16f(u32 u) { return __uint_as_float(u & 0xffff0000u); }

// ---------- in-kernel dtype detect (runs on every block, cheap/L2-hot) ----------
__device__ int detect_bf(const void* feat, int* cntL) {
    int t = threadIdx.x;
    if (t == 0) *cntL = 0;
    __syncthreads();
    const unsigned short* u = (const unsigned short*)feat;
    int local = 0;
    for (int i = t; i < 4096; i += blockDim.x) {
        float v = __uint_as_float(((u32)u[i]) << 16);
        float a = fabsf(v);
        if (a >= 1e-4f && a <= 100.f) local++;
    }
    atomicAdd(cntL, local);
    __syncthreads();
    return (*cntL > 3072) ? 1 : 0;
}

// ---------- block reductions (256 threads) ----------
__device__ inline float blk_sum(float v, float* sh) {
    for (int o = 32; o > 0; o >>= 1) v += __shfl_down(v, o, 64);
    int w = threadIdx.x >> 6;
    __syncthreads();
    if ((threadIdx.x & 63) == 0) sh[w] = v;
    __syncthreads();
    return sh[0] + sh[1] + sh[2] + sh[3];
}

// ================= 1: FUSED sim + softmax partial + pt partial =================
// 512 thr, tile = 128 positions. Phase 1: float4 loads (2 ch/wave-iter),
// dots in regs, bf16 tile staged (pair-XOR swizzle). Rounds reduce via 6KB red.
// Phase 2: channel-owner from LDS, broadcast weights, no shuffles.
template<bool BF>
__device__ void simpt_body(const void* feat, const void* mask, const void* temp,
                           const void* pq, float* ptp, float* mz, float* smem) {
    u32*   featU = (u32*)smem;                 // 16384 u32 (64 KB)
    float* reg   = smem + 16384;               // 1920: red[1536] / wL[640]+psum[1280]
    float* qL    = smem + 16384 + 1920;        // 1280 f32; simL aliases [0..639]
    float* simL  = qL;
    float* mL    = qL + 1280;                  // 128
    float* sc    = mL + 128;                   // scalars
    int t = threadIdx.x, lane = t & 63, q = t >> 6;
    int b = blockIdx.y, tile = blockIdx.x;

    // qnorm: waves 0..4 each normalize one query row (redundant per block, cheap)
    if (q < K_) {
        float4 v = LD4<BF>(pq, (size_t)q * C_ + lane * 4);
        float ss = v.x * v.x + v.y * v.y + v.z * v.z + v.w * v.w;
        for (int o = 32; o > 0; o >>= 1) ss += __shfl_xor(ss, o, 64);
        float inv = 1.0f / fmaxf(sqrtf(ss), 1e-12f);
        *(float4*)(qL + q * C_ + lane * 4) =
            make_float4(v.x * inv, v.y * inv, v.z * inv, v.w * inv);
    }
    if (t == 0) sc[0] = 1.0f / fmaxf(LD<BF>(temp, 0), 0.01f);
    if (t < 32) *(float4*)(mL + t * 4) = LD4<BF>(mask, (size_t)b * HW_ + tile * P_ + t * 4);
    __syncthreads();

    // ---- phase 1 ----
    int c0 = q * 32, half = lane >> 5, lm = lane & 31;
    float sa[4] = {0.f, 0.f, 0.f, 0.f};
    float da[K_][4];
    #pragma unroll
    for (int k = 0; k < K_; k++)
        #pragma unroll
        for (int i = 0; i < 4; i++) da[k][i] = 0.f;
    size_t gbase = (size_t)b * C_ * HW_ + (size_t)tile * P_ + lm * 4;
    #pragma unroll 4
    for (int j = 0; j < 16; j++) {
        int c = c0 + 2 * j + half;
        float4 f = LD4<BF>(feat, gbase + (size_t)c * HW_);
        sa[0] += f.x * f.x; sa[1] += f.y * f.y; sa[2] += f.z * f.z; sa[3] += f.w * f.w;
        #pragma unroll
        for (int k = 0; k < K_; k++) {
            float qv = qL[k * C_ + c];
            da[k][0] += f.x * qv; da[k][1] += f.y * qv;
            da[k][2] += f.z * qv; da[k][3] += f.w * qv;
        }
        int ps = lm ^ (c & 31);
        *(uint2*)&featU[c * 64 + 2 * ps] =
            make_uint2(packbf2(f.x, f.y), packbf2(f.z, f.w));
    }
    // combine channel-halves (lanes 0..31 valid after)
    #pragma unroll
    for (int i = 0; i < 4; i++) sa[i] += __shfl_down(sa[i], 32, 64);
    #pragma unroll
    for (int k = 0; k < K_; k++)
        #pragma unroll
        for (int i = 0; i < 4; i++) da[k][i] += __shfl_down(da[k][i], 32, 64);

    // ---- finalize rounds: position index i = r per round ----
    float* red = reg;   // 6*256
    for (int r = 0; r < 4; r++) {
        if (lane < 32) {
            red[0 * 256 + q * 32 + lane] = sa[r];
            #pragma unroll
            for (int k = 0; k < K_; k++) red[(1 + k) * 256 + q * 32 + lane] = da[k][r];
        }
        __syncthreads();
        if (t < 160) {
            int kk = t >> 5, m = t & 31, n = 4 * m + r;
            float ssum = 0.f, dsum = 0.f;
            #pragma unroll
            for (int g = 0; g < 8; g++) {
                ssum += red[0 * 256 + g * 32 + m];
                dsum += red[(1 + kk) * 256 + g * 32 + m];
            }
            simL[kk * P_ + n] = (mL[n] > 0.f)
                ? dsum * (sc[0] / fmaxf(sqrtf(ssum), 1e-12f)) : -INFINITY;
        }
        __syncthreads();
    }

    // ---- wave softmax partial per k ----
    float* wL   = reg;          // 640 (red dead)
    float* psum = reg + 640;    // 1280
    if (q < K_) {
        float s0 = simL[q * P_ + 2 * lane], s1 = simL[q * P_ + 2 * lane + 1];
        float m = fmaxf(s0, s1);
        for (int o = 32; o > 0; o >>= 1) m = fmaxf(m, __shfl_xor(m, o, 64));
        float e0 = (s0 == -INFINITY) ? 0.f : __expf(s0 - m);
        float e1 = (s1 == -INFINITY) ? 0.f : __expf(s1 - m);
        float z = e0 + e1;
        for (int o = 32; o > 0; o >>= 1) z += __shfl_xor(z, o, 64);
        *(float2*)(wL + q * P_ + 2 * lane) = make_float2(e0, e1);
        if (lane == 0) {
            size_t mzb = ((size_t)(b * NT_ + tile) * K_ + q) * 2;
            mz[mzb] = m; mz[mzb + 1] = z;
        }
    }
    __syncthreads();

    // ---- phase 2: channel-owner ----
    int cch = t & 255, h = t >> 8, x = cch & 31;
    float acc[K_] = {0.f, 0.f, 0.f, 0.f, 0.f};
    #pragma unroll 4
    for (int jj = 0; jj < 16; jj++) {
        int p = h * 16 + jj;
        uint2 v = *(const uint2*)&featU[cch * 64 + 2 * (p ^ x)];
        float f0 = lo16f(v.x), f1 = hi16f(v.x), f2 = lo16f(v.y), f3 = hi16f(v.y);
        #pragma unroll
        for (int k = 0; k < K_; k++) {
            float4 w4 = *(const float4*)(wL + k * P_ + 4 * p);   // broadcast
            acc[k] += f0 * w4.x + f1 * w4.y + f2 * w4.z + f3 * w4.w;
        }
    }
    if (h == 1) {
        #pragma unroll
        for (int k = 0; k < K_; k++) psum[k * C_ + cch] = acc[k];
    }
    __syncthreads();
    if (h == 0) {
        size_t pb = (size_t)(b * NT_ + tile) * (K_ * C_);
        #pragma unroll
        for (int k = 0; k < K_; k++)
            ptp[pb + k * C_ + cch] = acc[k] + psum[k * C_ + cch];
    }
}
__global__ __launch_bounds__(512, 4) void k_simpt(const void* feat, const void* mask,
                                                  const void* temp, const void* pq,
                                                  float* ptp, float* mz) {
    __shared__ __attribute__((aligned(16))) float smem[19720];
    __shared__ int cnt;
    int flg = detect_bf(feat, &cnt);
    if (flg) simpt_body<true >(feat, mask, temp, pq, ptp, mz, smem);
    else     simpt_body<false>(feat, mask, temp, pq, ptp, mz, smem);
}

// ================= 2: merge + prep + div in one kernel =================
__device__ inline float merge_one(const float* ptp, const float* mz,
                                  int b, int kk, int c) {
    float M = -INFINITY;
    #pragma unroll 8
    for (int tl = 0; tl < NT_; tl++)
        M = fmaxf(M, mz[((size_t)(b * NT_ + tl) * K_ + kk) * 2]);
    float Zs = 0.f, acc = 0.f;
    #pragma unroll 8
    for (int tl = 0; tl < NT_; tl++) {
        size_t mzb = ((size_t)(b * NT_ + tl) * K_ + kk) * 2;
        float m_t = mz[mzb], z_t = mz[mzb + 1];
        float s = (m_t == -INFINITY) ? 0.f : __expf(m_t - M);
        Zs += z_t * s;
        acc += ptp[(size_t)(b * NT_ + tl) * (K_ * C_) + kk * C_ + c] * s;
    }
    return (Zs > 0.f) ? acc / Zs : 0.f;
}
template<bool BF>
__device__ void prep_part(const void* qw, const void* kw, const void* kb,
                          const void* vw, const void* vb, const void* ow,
                          const void* bnw, const void* bnb, const void* bnm,
                          const void* bnv, float ptv, int bk,
                          float* W2, float* b2, float* OV, float* pt, float* smem) {
    float* ptL = smem;
    float* KtL = smem + 256;
    float* VtL = smem + 512;
    float* sh  = smem + 768;
    int t = threadIdx.x;
    ptL[t] = ptv;
    pt[(size_t)bk * C_ + t] = ptv;
    __syncthreads();
    float kt = LD<BF>(kb, t), vt = LD<BF>(vb, t);
    for (int c = 0; c < C_; c += 4) {
        float4 p4 = *(float4*)(ptL + c);
        float4 kw4 = LD4<BF>(kw, (size_t)t * C_ + c);
        float4 vw4 = LD4<BF>(vw, (size_t)t * C_ + c);
        kt += kw4.x * p4.x + kw4.y * p4.y + kw4.z * p4.z + kw4.w * p4.w;
        vt += vw4.x * p4.x + vw4.y * p4.y + vw4.z * p4.z + vw4.w * p4.w;
    }
    float scale = LD<BF>(bnw, t) * rsqrtf(LD<BF>(bnv, t) + 1e-5f);
    float shift = LD<BF>(bnb, t) - LD<BF>(bnm, t) * scale;
    KtL[t] = kt * scale;
    VtL[t] = vt;
    float bpart = kt * shift;
    __syncthreads();
    float ov = 0;
    for (int c = 0; c < C_; c += 4) {
        float4 v4 = *(float4*)(VtL + c);
        float4 ow4 = LD4<BF>(ow, (size_t)t * C_ + c);
        ov += ow4.x * v4.x + ow4.y * v4.y + ow4.z * v4.z + ow4.w * v4.w;
    }
    OV[(size_t)bk * C_ + t] = ov;
    float w2 = 0;
    for (int o = 0; o < C_; o++) w2 += KtL[o] * LD<BF>(qw, (size_t)o * C_ + t);
    W2[(size_t)bk * C_ + t] = w2 * (1.0f / 16.0f);
    float bs = blk_sum(bpart, sh);
    if (t == 0) b2[bk] = bs * (1.0f / 16.0f);
}
template<bool BF>
__device__ void div_part(const float* ptp, const float* mz, const void* margin,
                         float* divpart, float* smem) {
    float* ptL = smem;                 // 1280
    float* rn  = smem + K_ * C_;
    float* sh  = rn + 8;
    int b = blockIdx.x - B_ * K_, t = threadIdx.x;
    for (int kk = 0; kk < K_; kk++) ptL[kk * C_ + t] = merge_one(ptp, mz, b, kk, t);
    __syncthreads();
    for (int k = 0; k < K_; k++) {
        float v = ptL[k * C_ + t];
        float s = blk_sum(v * v, sh);
        if (t == 0) rn[k] = 1.0f / fmaxf(sqrtf(s), 1e-12f);
    }
    __syncthreads();
    float m = LD<BF>(margin, 0);
    m = fminf(fmaxf(m, 0.f), 0.5f);
    int p = t >> 3, g = t & 7;
    float contrib = 0.f;
    if (p < K_ * K_) {
        int k = p / K_, j = p % K_;
        float d = 0;
        for (int c = g; c < C_; c += 8) d += ptL[k * C_ + c] * ptL[j * C_ + c];
        d += __shfl_down(d, 4, 8);
        d += __shfl_down(d, 2, 8);
        d += __shfl_down(d, 1, 8);
        if (g == 0 && k != j) contrib = fmaxf(d * rn[k] * rn[j] - m, 0.f);
    }
    float s = blk_sum(contrib, sh);
    if (t == 0) divpart[b] = s;
}
template<bool BF>
__device__ void mergeprep_body(const void* qw, const void* kw, const void* kb,
                               const void* vw, const void* vb, const void* ow,
                               const void* bnw, const void* bnb, const void* bnm,
                               const void* bnv, const void* margin,
                               const float* ptp, const float* mz,
                               float* W2, float* b2, float* OV, float* pt,
                               float* divpart, float* smem) {
    int bid = blockIdx.x, t = threadIdx.x;
    if (bid < B_ * K_) {
        int b = bid / K_, kk = bid % K_;
        float ptv = merge_one(ptp, mz, b, kk, t);
        prep_part<BF>(qw, kw, kb, vw, vb, ow, bnw, bnb, bnm, bnv,
                      ptv, bid, W2, b2, OV, pt, smem);
    } else {
        div_part<BF>(ptp, mz, margin, divpart, smem);
    }
}
__global__ void k_mergeprep(const void* feat, const void* qw, const void* kw,
                            const void* kb, const void* vw, const void* vb,
                            const void* ow, const void* bnw, const void* bnb,
                            const void* bnm, const void* bnv, const void* margin,
                            const float* ptp, const float* mz,
                            float* W2, float* b2, float* OV, float* pt, float* divpart) {
    __shared__ __attribute__((aligned(16))) float smem[K_ * C_ + 16];
    __shared__ int cnt;
    int flg = detect_bf(feat, &cnt);
    if (flg) mergeprep_body<true >(qw, kw, kb, vw, vb, ow, bnw, bnb, bnm, bnv, margin,
                                   ptp, mz, W2, b2, OV, pt, divpart, smem);
    else     mergeprep_body<false>(qw, kw, kb, vw, vb, ow, bnw, bnb, bnm, bnv, margin,
                                   ptp, mz, W2, b2, OV, pt, divpart, smem);
}

// ================= 3: fused refine-attn + residual =================
template<bool BF>
__device__ void fin_body(const void* feat, const void* outb, const void* gamma,
                         const float* W2, const float* b2, const float* OV,
                         const float* pt, const float* divpart,
                         void* dout, float* smem) {
    u32*   featU = (u32*)smem;                 // 16384 (64 KB)
    float* red   = smem + 16384;               // 1280
    float* eL    = red + 1280;                 // 640
    u32*   W2p   = (u32*)(eL + 640);           // 640
    u32*   OVp   = W2p + 640;                  // 640
    float* obL   = (float*)(OVp + 640);        // 256
    float* b2L   = obL + 256;                  // 8
    int t = threadIdx.x, lane = t & 63, q = t >> 6;
    int b = blockIdx.y, tile = blockIdx.x;
    for (int i = t; i < 640; i += 512) {
        W2p[i] = packbf2(W2[(size_t)b * 1280 + 2 * i], W2[(size_t)b * 1280 + 2 * i + 1]);
        OVp[i] = packbf2(OV[(size_t)b * 1280 + 2 * i], OV[(size_t)b * 1280 + 2 * i + 1]);
    }
    if (t < C_) obL[t] = LD<BF>(outb, t);
    if (t < K_) b2L[t] = b2[b * K_ + t];
    __syncthreads();

    // ---- phase 1: logit partials + staging ----
    int c0 = q * 32, half = lane >> 5, lm = lane & 31;
    size_t gbase = (size_t)b * C_ * HW_ + (size_t)tile * P_ + lm * 4;
    float la[K_][4];
    #pragma unroll
    for (int k = 0; k < K_; k++)
        #pragma unroll
        for (int i = 0; i < 4; i++) la[k][i] = 0.f;
    #pragma unroll 4
    for (int j = 0; j < 16; j++) {
        int c = c0 + 2 * j + half;
        float4 f = LD4<BF>(feat, gbase + (size_t)c * HW_);
        #pragma unroll
        for (int k = 0; k < K_; k++) {
            u32 u = W2p[k * 128 + (c >> 1)];
            float wv = half ? hi16f(u) : lo16f(u);
            la[k][0] += f.x * wv; la[k][1] += f.y * wv;
            la[k][2] += f.z * wv; la[k][3] += f.w * wv;
        }
        int ps = lm ^ (c & 31);
        *(uint2*)&featU[c * 64 + 2 * ps] =
            make_uint2(packbf2(f.x, f.y), packbf2(f.z, f.w));
    }
    #pragma unroll
    for (int k = 0; k < K_; k++)
        #pragma unroll
        for (int i = 0; i < 4; i++) la[k][i] += __shfl_down(la[k][i], 32, 64);

    // ---- finalize rounds ----
    for (int r = 0; r < 4; r++) {
        if (lane < 32) {
            #pragma unroll
            for (int k = 0; k < K_; k++) red[k * 256 + q * 32 + lane] = la[k][r];
        }
        __syncthreads();
        if (t < 32) {
            int n = 4 * t + r;
            float lg[K_];
            #pragma unroll
            for (int k = 0; k < K_; k++) {
                float s = b2L[k];
                #pragma unroll
                for (int g = 0; g < 8; g++) s += red[k * 256 + g * 32 + t];
                lg[k] = s;
            }
            float mx = fmaxf(fmaxf(fmaxf(lg[0], lg[1]), fmaxf(lg[2], lg[3])), lg[4]);
            float e0 = __expf(lg[0] - mx), e1 = __expf(lg[1] - mx),
                  e2 = __expf(lg[2] - mx), e3 = __expf(lg[3] - mx),
                  e4 = __expf(lg[4] - mx);
            float inv = 1.0f / (e0 + e1 + e2 + e3 + e4);
            eL[0 * P_ + n] = e0 * inv; eL[1 * P_ + n] = e1 * inv;
            eL[2 * P_ + n] = e2 * inv; eL[3 * P_ + n] = e3 * inv;
            eL[4 * P_ + n] = e4 * inv;
        }
        __syncthreads();
    }

    // ---- phase 2: output, coalesced ST2 ----
    float g = LD<BF>(gamma, 0);
    float2 ek[K_];
    #pragma unroll
    for (int k = 0; k < K_; k++) ek[k] = *(const float2*)(eL + k * P_ + 2 * lane);
    size_t obase = (size_t)b * C_ * HW_ + (size_t)tile * P_ + 2 * lane;
    #pragma unroll 4
    for (int cc = 0; cc < 32; cc++) {
        int c = c0 + cc, x = c & 31;
        u32 v = featU[c * 64 + 2 * ((lane >> 1) ^ x) + (lane & 1)];
        float f0 = lo16f(v), f1 = hi16f(v);
        float ob = obL[c];
        float a0 = ob, a1 = ob;
        #pragma unroll
        for (int k = 0; k < K_; k++) {
            u32 u = OVp[k * 128 + (c >> 1)];
            float ov = (c & 1) ? hi16f(u) : lo16f(u);
            a0 += ek[k].x * ov; a1 += ek[k].y * ov;
        }
        ST2<BF>(dout, obase + (size_t)c * HW_, make_float2(f0 + g * a0, f1 + g * a1));
    }
    // aux outputs (b==0 slice)
    if (b == 0) {
        const size_t enh = (size_t)B_ * C_ * HW_;
        for (int i = blockIdx.x * 512 + t; i < B_ * K_ * C_; i += NT_ * 512)
            ST<BF>(dout, enh + 1 + i, pt[i]);
        if (blockIdx.x == 0 && t == 0) {
            float s = 0;
            for (int bb = 0; bb < B_; bb++) s += divpart[bb];
            ST<BF>(dout, enh, s / (640.0f + 1e-5f));
        }
    }
}
__global__ __launch_bounds__(512, 4) void k_fin(const void* feat, const void* outb,
                                                const void* gamma, const float* W2,
                                                const float* b2, const float* OV,
                                                const float* pt, const float* divpart,
                                                void* dout) {
    __shared__ __attribute__((aligned(16))) float smem[19848];
    __shared__ int cnt;
    int flg = detect_bf(feat, &cnt);
    if (flg) fin_body<true >(feat, outb, gamma, W2, b2, OV, pt, divpart, dout, smem);
    else     fin_body<false>(feat, outb, gamma, W2, b2, OV, pt, divpart, dout, smem);
}

extern "C" void kernel_launch(void* const* d_in, const int* in_sizes, int n_in,
                              void* d_out, int out_size, void* d_ws, size_t ws_size,
                              hipStream_t stream) {
    const void* feat = d_in[0];
    const void* mask = d_in[1];
    const void* pq   = d_in[2];
    const void* temp = d_in[3];
    const void* marg = d_in[4];
    const void* qw   = d_in[5];
    const void* bnw  = d_in[6];
    const void* bnb  = d_in[7];
    const void* bnm  = d_in[8];
    const void* bnv  = d_in[9];
    const void* kw   = d_in[10];
    const void* kb   = d_in[11];
    const void* vw   = d_in[12];
    const void* vb   = d_in[13];
    const void* ow   = d_in[14];
    const void* ob   = d_in[15];
    const void* gm   = d_in[16];

    float* ws  = (float*)d_ws;
    float* ptp = ws;                                    // B*NT*K*C = 1,310,720
    float* mz  = ptp + (size_t)B_ * NT_ * K_ * C_;      // B*NT*K*2 = 10,240
    float* pt  = mz  + (size_t)B_ * NT_ * K_ * 2;       // 40,960
    float* W2  = pt  + B_ * K_ * C_;                    // 40,960
    float* b2  = W2  + B_ * K_ * C_;                    // 160
    float* OV  = b2  + B_ * K_;                         // 40,960
    float* dvp = OV  + B_ * K_ * C_;                    // 32

    hipLaunchKernelGGL(k_simpt, dim3(NT_, B_), dim3(512), 0, stream,
                       feat, mask, temp, pq, ptp, mz);
    hipLaunchKernelGGL(k_mergeprep, dim3(B_ * K_ + B_), dim3(256), 0, stream,
                       feat, qw, kw, kb, vw, vb, ow, bnw, bnb, bnm, bnv, marg,
                       ptp, mz, W2, b2, OV, pt, dvp);
    hipLaunchKernelGGL(k_fin, dim3(NT_, B_), dim3(512), 0, stream,
                       feat, ob, gm, W2, b2, OV, pt, dvp, d_out);
}

// Round 8
// 148.462 us; speedup vs baseline: 1.9685x; 1.0892x over previous
//
#include <hip/hip_runtime.h>
#include <hip/hip_bf16.h>
#include <math.h>

#define B_  32
#define C_  256
#define HW_ 4096
#define K_  5
#define P_  128          // positions per tile
#define NT_ 32           // HW_/P_
#define PS_ 68           // padded LDS row stride (u32 words) for featB/wB

typedef __hip_bfloat16 bf16;
typedef unsigned int u32;
typedef __attribute__((ext_vector_type(8))) short bf16x8;
typedef __attribute__((ext_vector_type(4))) float f32x4;

// ---------- dtype-flexible load/store ----------
template<bool BF>
__device__ inline float LD(const void* p, size_t i) {
    if (BF) return __bfloat162float(((const bf16*)p)[i]);
    return ((const float*)p)[i];
}
template<bool BF>
__device__ inline void ST(void* p, size_t i, float v) {
    if (BF) ((bf16*)p)[i] = __float2bfloat16(v);
    else    ((float*)p)[i] = v;
}
template<bool BF>
__device__ inline float4 LD4(const void* p, size_t i) {
    if (BF) {
        ushort4 u = *(const ushort4*)((const unsigned short*)p + i);
        float4 r;
        r.x = __uint_as_float(((u32)u.x) << 16);
        r.y = __uint_as_float(((u32)u.y) << 16);
        r.z = __uint_as_float(((u32)u.z) << 16);
        r.w = __uint_as_float(((u32)u.w) << 16);
        return r;
    }
    return *(const float4*)((const float*)p + i);
}
template<bool BF>
__device__ inline void ST2(void* p, size_t i, float2 v) {
    if (BF) {
        bf16 a = __float2bfloat16(v.x), b = __float2bfloat16(v.y);
        ushort2 u;
        u.x = *(unsigned short*)&a; u.y = *(unsigned short*)&b;
        *(ushort2*)((unsigned short*)p + i) = u;
    } else {
        *(float2*)((float*)p + i) = v;
    }
}
__device__ inline u32 packbf2(float a, float b) {   // a -> low 16
    bf16 x = __float2bfloat16(a), y = __float2bfloat16(b);
    return (((u32)*(unsigned short*)&y) << 16) | (u32)(*(unsigned short*)&x);
}
__device__ inline float lo16f(u32 u) { return __uint_as_float(u << 16); }
__device__ inline float hi16f(u32 u) { return __uint_as_float(u & 0xffff0000u); }

// ---------- in-kernel dtype detect (wave-reduced, 1 atomic per wave) ----------
__device__ int detect_bf(const void* feat, int* cntL) {
    int t = threadIdx.x;
    if (t == 0) *cntL = 0;
    __syncthreads();
    const unsigned short* u = (const unsigned short*)feat;
    int local = 0;
    for (int i = t; i < 4096; i += blockDim.x) {
        float v = __uint_as_float(((u32)u[i]) << 16);
        float a = fabsf(v);
        local += (a >= 1e-4f && a <= 100.f) ? 1 : 0;
    }
    for (int o = 32; o > 0; o >>= 1) local += __shfl_down(local, o, 64);
    if ((t & 63) == 0) atomicAdd(cntL, local);
    __syncthreads();
    return (*cntL > 3072) ? 1 : 0;
}

// ---------- block reductions (256 threads) ----------
__device__ inline float blk_sum(float v, float* sh) {
    for (int o = 32; o > 0; o >>= 1) v += __shfl_down(v, o, 64);
    int w = threadIdx.x >> 6;
    __syncthreads();
    if ((threadIdx.x & 63) == 0) sh[w] = v;
    __syncthreads();
    return sh[0] + sh[1] + sh[2] + sh[3];
}

// ================= 1: FUSED sim + softmax partial + pt partial (MFMA) ==========
// 512 thr (8 waves x 32ch), tile = 128 positions.
// phase 1: float4 feat loads -> 6 partial dots in regs + bf16 tile staged
//          linearly at padded stride PS_ (MFMA-A-fragment friendly).
// finalize: 4 rounds via red -> simL; wave softmax -> bf16 wB (B operand).
// phase 2: 64x mfma_f32_16x16x32_bf16 per block; D col = query k, row = channel.
template<bool BF>
__device__ void simpt_body(const void* feat, const void* mask, const void* temp,
                           const void* pq, float* ptp, float* mz, float* smem) {
    u32*   featB = (u32*)smem;                 // [256][PS_] = 17408 u32 (68 KB)
    float* red   = smem + 17408;               // 1536 f32 (finalize rounds)
    u32*   wB    = (u32*)red;                  // alias: [16][PS_], rows 0..4 valid
    float* qL    = smem + 17408 + 1536;        // 1280 f32
    float* simL  = qL;                         // alias after phase 1 (640 used)
    float* sc    = qL + 1280;                  // scalars
    int t = threadIdx.x, lane = t & 63, q = t >> 6;
    int b = blockIdx.y, tile = blockIdx.x;

    // qnorm: waves 0..4 each normalize one query row
    if (q < K_) {
        float4 v = LD4<BF>(pq, (size_t)q * C_ + lane * 4);
        float ss = v.x * v.x + v.y * v.y + v.z * v.z + v.w * v.w;
        for (int o = 32; o > 0; o >>= 1) ss += __shfl_xor(ss, o, 64);
        float inv = 1.0f / fmaxf(sqrtf(ss), 1e-12f);
        *(float4*)(qL + q * C_ + lane * 4) =
            make_float4(v.x * inv, v.y * inv, v.z * inv, v.w * inv);
    }
    if (t == 0) sc[0] = 1.0f / fmaxf(LD<BF>(temp, 0), 0.01f);
    __syncthreads();

    // ---- phase 1 ----
    int c0 = q * 32, half = lane >> 5, lm = lane & 31;
    float sa[4] = {0.f, 0.f, 0.f, 0.f};
    float da[K_][4];
    #pragma unroll
    for (int k = 0; k < K_; k++)
        #pragma unroll
        for (int i = 0; i < 4; i++) da[k][i] = 0.f;
    size_t gbase = (size_t)b * C_ * HW_ + (size_t)tile * P_ + lm * 4;
    #pragma unroll 4
    for (int j = 0; j < 16; j++) {
        int c = c0 + 2 * j + half;
        float4 f = LD4<BF>(feat, gbase + (size_t)c * HW_);
        sa[0] += f.x * f.x; sa[1] += f.y * f.y; sa[2] += f.z * f.z; sa[3] += f.w * f.w;
        #pragma unroll
        for (int k = 0; k < K_; k++) {
            float qv = qL[k * C_ + c];
            da[k][0] += f.x * qv; da[k][1] += f.y * qv;
            da[k][2] += f.z * qv; da[k][3] += f.w * qv;
        }
        // linear bf16 staging: row c, words 2*lm, 2*lm+1 (positions 4lm..4lm+3)
        *(uint2*)&featB[c * PS_ + 2 * lm] =
            make_uint2(packbf2(f.x, f.y), packbf2(f.z, f.w));
    }
    // combine channel-halves (lanes 0..31 valid after)
    #pragma unroll
    for (int i = 0; i < 4; i++) sa[i] += __shfl_down(sa[i], 32, 64);
    #pragma unroll
    for (int k = 0; k < K_; k++)
        #pragma unroll
        for (int i = 0; i < 4; i++) da[k][i] += __shfl_down(da[k][i], 32, 64);

    // ---- finalize rounds: position i = 4*m + r ----
    float tinv = sc[0];
    for (int r = 0; r < 4; r++) {
        if (lane < 32) {
            red[0 * 256 + q * 32 + lane] = sa[r];
            #pragma unroll
            for (int k = 0; k < K_; k++) red[(1 + k) * 256 + q * 32 + lane] = da[k][r];
        }
        __syncthreads();
        if (t < 160) {
            int kk = t >> 5, m = t & 31, n = 4 * m + r;
            float ssum = 0.f, dsum = 0.f;
            #pragma unroll
            for (int g = 0; g < 8; g++) {
                ssum += red[0 * 256 + g * 32 + m];
                dsum += red[(1 + kk) * 256 + g * 32 + m];
            }
            float mval = LD<BF>(mask, (size_t)b * HW_ + tile * P_ + n);
            simL[kk * P_ + n] = (mval > 0.f)
                ? dsum * (tinv / fmaxf(sqrtf(ssum), 1e-12f)) : -INFINITY;
        }
        __syncthreads();
    }

    // ---- wave softmax partial per k -> bf16 wB (red dead, aliased) ----
    if (q < K_) {
        float s0 = simL[q * P_ + 2 * lane], s1 = simL[q * P_ + 2 * lane + 1];
        float m = fmaxf(s0, s1);
        for (int o = 32; o > 0; o >>= 1) m = fmaxf(m, __shfl_xor(m, o, 64));
        float e0 = (s0 == -INFINITY) ? 0.f : __expf(s0 - m);
        float e1 = (s1 == -INFINITY) ? 0.f : __expf(s1 - m);
        float z = e0 + e1;
        for (int o = 32; o > 0; o >>= 1) z += __shfl_xor(z, o, 64);
        wB[q * PS_ + lane] = packbf2(e0, e1);   // positions 2*lane, 2*lane+1
        if (lane == 0) {
            size_t mzb = ((size_t)(b * NT_ + tile) * K_ + q) * 2;
            mz[mzb] = m; mz[mzb + 1] = z;
        }
    }
    __syncthreads();

    // ---- phase 2: MFMA. D[row=channel][col=query-k] = feat[c][p] x w (B) ----
    int r16 = lane & 15, g = lane >> 4;
    size_t pb = (size_t)(b * NT_ + tile) * (K_ * C_);
    #pragma unroll
    for (int sub = 0; sub < 2; sub++) {
        int ctile = q * 32 + sub * 16;
        f32x4 acc = {0.f, 0.f, 0.f, 0.f};
        #pragma unroll
        for (int s = 0; s < 4; s++) {
            bf16x8 a = *(const bf16x8*)(featB + (ctile + r16) * PS_ + 16 * s + 4 * g);
            bf16x8 bb = *(const bf16x8*)(wB + r16 * PS_ + 16 * s + 4 * g);
            acc = __builtin_amdgcn_mfma_f32_16x16x32_bf16(a, bb, acc, 0, 0, 0);
        }
        if (r16 < K_) {
            #pragma unroll
            for (int r = 0; r < 4; r++)
                ptp[pb + (size_t)r16 * C_ + ctile + 4 * g + r] = acc[r];
        }
    }
}
__global__ __launch_bounds__(512, 4) void k_simpt(const void* feat, const void* mask,
                                                  const void* temp, const void* pq,
                                                  float* ptp, float* mz) {
    __shared__ __attribute__((aligned(16))) float smem[20232];   // 80,928 B
    __shared__ int cnt;
    int flg = detect_bf(feat, &cnt);
    if (flg) simpt_body<true >(feat, mask, temp, pq, ptp, mz, smem);
    else     simpt_body<false>(feat, mask, temp, pq, ptp, mz, smem);
}

// ================= 2: merge + prep + div in one kernel =================
__device__ inline float merge_one(const float* ptp, const float* mz,
                                  int b, int kk, int c) {
    float M = -INFINITY;
    #pragma unroll 8
    for (int tl = 0; tl < NT_; tl++)
        M = fmaxf(M, mz[((size_t)(b * NT_ + tl) * K_ + kk) * 2]);
    float Zs = 0.f, acc = 0.f;
    #pragma unroll 8
    for (int tl = 0; tl < NT_; tl++) {
        size_t mzb = ((size_t)(b * NT_ + tl) * K_ + kk) * 2;
        float m_t = mz[mzb], z_t = mz[mzb + 1];
        float s = (m_t == -INFINITY) ? 0.f : __expf(m_t - M);
        Zs += z_t * s;
        acc += ptp[(size_t)(b * NT_ + tl) * (K_ * C_) + kk * C_ + c] * s;
    }
    return (Zs > 0.f) ? acc / Zs : 0.f;
}
template<bool BF>
__device__ void prep_part(const void* qw, const void* kw, const void* kb,
                          const void* vw, const void* vb, const void* ow,
                          const void* bnw, const void* bnb, const void* bnm,
                          const void* bnv, float ptv, int bk,
                          float* W2, float* b2, float* OV, float* pt, float* smem) {
    float* ptL = smem;
    float* KtL = smem + 256;
    float* VtL = smem + 512;
    float* sh  = smem + 768;
    int t = threadIdx.x;
    ptL[t] = ptv;
    pt[(size_t)bk * C_ + t] = ptv;
    __syncthreads();
    float kt = LD<BF>(kb, t), vt = LD<BF>(vb, t);
    for (int c = 0; c < C_; c += 4) {
        float4 p4 = *(float4*)(ptL + c);
        float4 kw4 = LD4<BF>(kw, (size_t)t * C_ + c);
        float4 vw4 = LD4<BF>(vw, (size_t)t * C_ + c);
        kt += kw4.x * p4.x + kw4.y * p4.y + kw4.z * p4.z + kw4.w * p4.w;
        vt += vw4.x * p4.x + vw4.y * p4.y + vw4.z * p4.z + vw4.w * p4.w;
    }
    float scale = LD<BF>(bnw, t) * rsqrtf(LD<BF>(bnv, t) + 1e-5f);
    float shift = LD<BF>(bnb, t) - LD<BF>(bnm, t) * scale;
    KtL[t] = kt * scale;
    VtL[t] = vt;
    float bpart = kt * shift;
    __syncthreads();
    float ov = 0;
    for (int c = 0; c < C_; c += 4) {
        float4 v4 = *(float4*)(VtL + c);
        float4 ow4 = LD4<BF>(ow, (size_t)t * C_ + c);
        ov += ow4.x * v4.x + ow4.y * v4.y + ow4.z * v4.z + ow4.w * v4.w;
    }
    OV[(size_t)bk * C_ + t] = ov;
    float w2 = 0;
    for (int o = 0; o < C_; o++) w2 += KtL[o] * LD<BF>(qw, (size_t)o * C_ + t);
    W2[(size_t)bk * C_ + t] = w2 * (1.0f / 16.0f);
    float bs = blk_sum(bpart, sh);
    if (t == 0) b2[bk] = bs * (1.0f / 16.0f);
}
template<bool BF>
__device__ void div_part(const float* ptp, const float* mz, const void* margin,
                         float* divpart, float* smem) {
    float* ptL = smem;                 // 1280
    float* rn  = smem + K_ * C_;
    float* sh  = rn + 8;
    int b = blockIdx.x - B_ * K_, t = threadIdx.x;
    for (int kk = 0; kk < K_; kk++) ptL[kk * C_ + t] = merge_one(ptp, mz, b, kk, t);
    __syncthreads();
    for (int k = 0; k < K_; k++) {
        float v = ptL[k * C_ + t];
        float s = blk_sum(v * v, sh);
        if (t == 0) rn[k] = 1.0f / fmaxf(sqrtf(s), 1e-12f);
    }
    __syncthreads();
    float m = LD<BF>(margin, 0);
    m = fminf(fmaxf(m, 0.f), 0.5f);
    int p = t >> 3, g = t & 7;
    float contrib = 0.f;
    if (p < K_ * K_) {
        int k = p / K_, j = p % K_;
        float d = 0;
        for (int c = g; c < C_; c += 8) d += ptL[k * C_ + c] * ptL[j * C_ + c];
        d += __shfl_down(d, 4, 8);
        d += __shfl_down(d, 2, 8);
        d += __shfl_down(d, 1, 8);
        if (g == 0 && k != j) contrib = fmaxf(d * rn[k] * rn[j] - m, 0.f);
    }
    float s = blk_sum(contrib, sh);
    if (t == 0) divpart[b] = s;
}
template<bool BF>
__device__ void mergeprep_body(const void* qw, const void* kw, const void* kb,
                               const void* vw, const void* vb, const void* ow,
                               const void* bnw, const void* bnb, const void* bnm,
                               const void* bnv, const void* margin,
                               const float* ptp, const float* mz,
                               float* W2, float* b2, float* OV, float* pt,
                               float* divpart, float* smem) {
    int bid = blockIdx.x, t = threadIdx.x;
    if (bid < B_ * K_) {
        int b = bid / K_, kk = bid % K_;
        float ptv = merge_one(ptp, mz, b, kk, t);
        prep_part<BF>(qw, kw, kb, vw, vb, ow, bnw, bnb, bnm, bnv,
                      ptv, bid, W2, b2, OV, pt, smem);
    } else {
        div_part<BF>(ptp, mz, margin, divpart, smem);
    }
}
__global__ void k_mergeprep(const void* feat, const void* qw, const void* kw,
                            const void* kb, const void* vw, const void* vb,
                            const void* ow, const void* bnw, const void* bnb,
                            const void* bnm, const void* bnv, const void* margin,
                            const float* ptp, const float* mz,
                            float* W2, float* b2, float* OV, float* pt, float* divpart) {
    __shared__ __attribute__((aligned(16))) float smem[K_ * C_ + 16];
    __shared__ int cnt;
    int flg = detect_bf(feat, &cnt);
    if (flg) mergeprep_body<true >(qw, kw, kb, vw, vb, ow, bnw, bnb, bnm, bnv, margin,
                                   ptp, mz, W2, b2, OV, pt, divpart, smem);
    else     mergeprep_body<false>(qw, kw, kb, vw, vb, ow, bnw, bnb, bnm, bnv, margin,
                                   ptp, mz, W2, b2, OV, pt, divpart, smem);
}

// ================= 3: fused refine-attn + residual =================
template<bool BF>
__device__ void fin_body(const void* feat, const void* outb, const void* gamma,
                         const float* W2, const float* b2, const float* OV,
                         const float* pt, const float* divpart,
                         void* dout, float* smem) {
    u32*   featU = (u32*)smem;                 // 16384 (64 KB)
    float* red   = smem + 16384;               // 1280
    float* eL    = red + 1280;                 // 640
    u32*   W2p   = (u32*)(eL + 640);           // 640
    u32*   OVp   = W2p + 640;                  // 640
    float* obL   = (float*)(OVp + 640);        // 256
    float* b2L   = obL + 256;                  // 8
    int t = threadIdx.x, lane = t & 63, q = t >> 6;
    int b = blockIdx.y, tile = blockIdx.x;
    for (int i = t; i < 640; i += 512) {
        W2p[i] = packbf2(W2[(size_t)b * 1280 + 2 * i], W2[(size_t)b * 1280 + 2 * i + 1]);
        OVp[i] = packbf2(OV[(size_t)b * 1280 + 2 * i], OV[(size_t)b * 1280 + 2 * i + 1]);
    }
    if (t < C_) obL[t] = LD<BF>(outb, t);
    if (t < K_) b2L[t] = b2[b * K_ + t];
    __syncthreads();

    // ---- phase 1: logit partials + staging ----
    int c0 = q * 32, half = lane >> 5, lm = lane & 31;
    size_t gbase = (size_t)b * C_ * HW_ + (size_t)tile * P_ + lm * 4;
    float la[K_][4];
    #pragma unroll
    for (int k = 0; k < K_; k++)
        #pragma unroll
        for (int i = 0; i < 4; i++) la[k][i] = 0.f;
    #pragma unroll 4
    for (int j = 0; j < 16; j++) {
        int c = c0 + 2 * j + half;
        float4 f = LD4<BF>(feat, gbase + (size_t)c * HW_);
        #pragma unroll
        for (int k = 0; k < K_; k++) {
            u32 u = W2p[k * 128 + (c >> 1)];
            float wv = half ? hi16f(u) : lo16f(u);
            la[k][0] += f.x * wv; la[k][1] += f.y * wv;
            la[k][2] += f.z * wv; la[k][3] += f.w * wv;
        }
        int ps = lm ^ (c & 31);
        *(uint2*)&featU[c * 64 + 2 * ps] =
            make_uint2(packbf2(f.x, f.y), packbf2(f.z, f.w));
    }
    #pragma unroll
    for (int k = 0; k < K_; k++)
        #pragma unroll
        for (int i = 0; i < 4; i++) la[k][i] += __shfl_down(la[k][i], 32, 64);

    // ---- finalize rounds ----
    for (int r = 0; r < 4; r++) {
        if (lane < 32) {
            #pragma unroll
            for (int k = 0; k < K_; k++) red[k * 256 + q * 32 + lane] = la[k][r];
        }
        __syncthreads();
        if (t < 32) {
            int n = 4 * t + r;
            float lg[K_];
            #pragma unroll
            for (int k = 0; k < K_; k++) {
                float s = b2L[k];
                #pragma unroll
                for (int g = 0; g < 8; g++) s += red[k * 256 + g * 32 + t];
                lg[k] = s;
            }
            float mx = fmaxf(fmaxf(fmaxf(lg[0], lg[1]), fmaxf(lg[2], lg[3])), lg[4]);
            float e0 = __expf(lg[0] - mx), e1 = __expf(lg[1] - mx),
                  e2 = __expf(lg[2] - mx), e3 = __expf(lg[3] - mx),
                  e4 = __expf(lg[4] - mx);
            float inv = 1.0f / (e0 + e1 + e2 + e3 + e4);
            eL[0 * P_ + n] = e0 * inv; eL[1 * P_ + n] = e1 * inv;
            eL[2 * P_ + n] = e2 * inv; eL[3 * P_ + n] = e3 * inv;
            eL[4 * P_ + n] = e4 * inv;
        }
        __syncthreads();
    }

    // ---- phase 2: output, coalesced ST2 ----
    float g = LD<BF>(gamma, 0);
    float2 ek[K_];
    #pragma unroll
    for (int k = 0; k < K_; k++) ek[k] = *(const float2*)(eL + k * P_ + 2 * lane);
    size_t obase = (size_t)b * C_ * HW_ + (size_t)tile * P_ + 2 * lane;
    #pragma unroll 4
    for (int cc = 0; cc < 32; cc++) {
        int c = c0 + cc, x = c & 31;
        u32 v = featU[c * 64 + 2 * ((lane >> 1) ^ x) + (lane & 1)];
        float f0 = lo16f(v), f1 = hi16f(v);
        float ob = obL[c];
        float a0 = ob, a1 = ob;
        #pragma unroll
        for (int k = 0; k < K_; k++) {
            u32 u = OVp[k * 128 + (c >> 1)];
            float ov = (c & 1) ? hi16f(u) : lo16f(u);
            a0 += ek[k].x * ov; a1 += ek[k].y * ov;
        }
        ST2<BF>(dout, obase + (size_t)c * HW_, make_float2(f0 + g * a0, f1 + g * a1));
    }
    // aux outputs (b==0 slice)
    if (b == 0) {
        const size_t enh = (size_t)B_ * C_ * HW_;
        for (int i = blockIdx.x * 512 + t; i < B_ * K_ * C_; i += NT_ * 512)
            ST<BF>(dout, enh + 1 + i, pt[i]);
        if (blockIdx.x == 0 && t == 0) {
            float s = 0;
            for (int bb = 0; bb < B_; bb++) s += divpart[bb];
            ST<BF>(dout, enh, s / (640.0f + 1e-5f));
        }
    }
}
__global__ __launch_bounds__(512, 4) void k_fin(const void* feat, const void* outb,
                                                const void* gamma, const float* W2,
                                                const float* b2, const float* OV,
                                                const float* pt, const float* divpart,
                                                void* dout) {
    __shared__ __attribute__((aligned(16))) float smem[19848];
    __shared__ int cnt;
    int flg = detect_bf(feat, &cnt);
    if (flg) fin_body<true >(feat, outb, gamma, W2, b2, OV, pt, divpart, dout, smem);
    else     fin_body<false>(feat, outb, gamma, W2, b2, OV, pt, divpart, dout, smem);
}

extern "C" void kernel_launch(void* const* d_in, const int* in_sizes, int n_in,
                              void* d_out, int out_size, void* d_ws, size_t ws_size,
                              hipStream_t stream) {
    const void* feat = d_in[0];
    const void* mask = d_in[1];
    const void* pq   = d_in[2];
    const void* temp = d_in[3];
    const void* marg = d_in[4];
    const void* qw   = d_in[5];
    const void* bnw  = d_in[6];
    const void* bnb  = d_in[7];
    const void* bnm  = d_in[8];
    const void* bnv  = d_in[9];
    const void* kw   = d_in[10];
    const void* kb   = d_in[11];
    const void* vw   = d_in[12];
    const void* vb   = d_in[13];
    const void* ow   = d_in[14];
    const void* ob   = d_in[15];
    const void* gm   = d_in[16];

    float* ws  = (float*)d_ws;
    float* ptp = ws;                                    // B*NT*K*C = 1,310,720
    float* mz  = ptp + (size_t)B_ * NT_ * K_ * C_;      // B*NT*K*2 = 10,240
    float* pt  = mz  + (size_t)B_ * NT_ * K_ * 2;       // 40,960
    float* W2  = pt  + B_ * K_ * C_;                    // 40,960
    float* b2  = W2  + B_ * K_ * C_;                    // 160
    float* OV  = b2  + B_ * K_;                         // 40,960
    float* dvp = OV  + B_ * K_ * C_;                    // 32

    hipLaunchKernelGGL(k_simpt, dim3(NT_, B_), dim3(512), 0, stream,
                       feat, mask, temp, pq, ptp, mz);
    hipLaunchKernelGGL(k_mergeprep, dim3(B_ * K_ + B_), dim3(256), 0, stream,
                       feat, qw, kw, kb, vw, vb, ow, bnw, bnb, bnm, bnv, marg,
                       ptp, mz, W2, b2, OV, pt, dvp);
    hipLaunchKernelGGL(k_fin, dim3(NT_, B_), dim3(512), 0, stream,
                       feat, ob, gm, W2, b2, OV, pt, dvp, d_out);
}

// Round 10
// 142.472 us; speedup vs baseline: 2.0513x; 1.0420x over previous
//
#include <hip/hip_runtime.h>
#include <hip/hip_bf16.h>
#include <math.h>

#define B_  32
#define C_  256
#define HW_ 4096
#define K_  5
#define P_  128          // positions per tile
#define NT_ 32           // HW_/P_
#define PS_ 68           // padded LDS row stride (u32 words) for featB/wB (k_simpt)
#define FS_ 66           // featU row stride (u32 words) in k_fin

typedef __hip_bfloat16 bf16;
typedef unsigned int u32;
typedef __attribute__((ext_vector_type(8))) short bf16x8;
typedef __attribute__((ext_vector_type(4))) float f32x4;

// ---------- dtype-flexible load/store ----------
template<bool BF>
__device__ inline float LD(const void* p, size_t i) {
    if (BF) return __bfloat162float(((const bf16*)p)[i]);
    return ((const float*)p)[i];
}
template<bool BF>
__device__ inline void ST(void* p, size_t i, float v) {
    if (BF) ((bf16*)p)[i] = __float2bfloat16(v);
    else    ((float*)p)[i] = v;
}
template<bool BF>
__device__ inline float4 LD4(const void* p, size_t i) {
    if (BF) {
        ushort4 u = *(const ushort4*)((const unsigned short*)p + i);
        float4 r;
        r.x = __uint_as_float(((u32)u.x) << 16);
        r.y = __uint_as_float(((u32)u.y) << 16);
        r.z = __uint_as_float(((u32)u.z) << 16);
        r.w = __uint_as_float(((u32)u.w) << 16);
        return r;
    }
    return *(const float4*)((const float*)p + i);
}
__device__ inline u32 packbf2(float a, float b) {   // a -> low 16
    bf16 x = __float2bfloat16(a), y = __float2bfloat16(b);
    return (((u32)*(unsigned short*)&y) << 16) | (u32)(*(unsigned short*)&x);
}
__device__ inline float lo16f(u32 u) { return __uint_as_float(u << 16); }
__device__ inline float hi16f(u32 u) { return __uint_as_float(u & 0xffff0000u); }

// ---------- in-kernel dtype detect (wave-reduced, 1 atomic per wave) ----------
__device__ int detect_bf(const void* feat, int* cntL) {
    int t = threadIdx.x;
    if (t == 0) *cntL = 0;
    __syncthreads();
    const unsigned short* u = (const unsigned short*)feat;
    int local = 0;
    for (int i = t; i < 4096; i += blockDim.x) {
        float v = __uint_as_float(((u32)u[i]) << 16);
        float a = fabsf(v);
        local += (a >= 1e-4f && a <= 100.f) ? 1 : 0;
    }
    for (int o = 32; o > 0; o >>= 1) local += __shfl_down(local, o, 64);
    if ((t & 63) == 0) atomicAdd(cntL, local);
    __syncthreads();
    return (*cntL > 3072) ? 1 : 0;
}

// ---------- block reductions (256 threads) ----------
__device__ inline float blk_sum(float v, float* sh) {
    for (int o = 32; o > 0; o >>= 1) v += __shfl_down(v, o, 64);
    int w = threadIdx.x >> 6;
    __syncthreads();
    if ((threadIdx.x & 63) == 0) sh[w] = v;
    __syncthreads();
    return sh[0] + sh[1] + sh[2] + sh[3];
}

// ================= 1: FUSED sim + softmax partial + pt partial (MFMA) ==========
// (unchanged from R8 — verified)
template<bool BF>
__device__ void simpt_body(const void* feat, const void* mask, const void* temp,
                           const void* pq, float* ptp, float* mz, float* smem) {
    u32*   featB = (u32*)smem;                 // [256][PS_] = 17408 u32 (68 KB)
    float* red   = smem + 17408;               // 1536 f32 (finalize rounds)
    u32*   wB    = (u32*)red;                  // alias: [16][PS_], rows 0..4 valid
    float* qL    = smem + 17408 + 1536;        // 1280 f32
    float* simL  = qL;                         // alias after phase 1 (640 used)
    float* sc    = qL + 1280;                  // scalars
    int t = threadIdx.x, lane = t & 63, q = t >> 6;
    int b = blockIdx.y, tile = blockIdx.x;

    if (q < K_) {
        float4 v = LD4<BF>(pq, (size_t)q * C_ + lane * 4);
        float ss = v.x * v.x + v.y * v.y + v.z * v.z + v.w * v.w;
        for (int o = 32; o > 0; o >>= 1) ss += __shfl_xor(ss, o, 64);
        float inv = 1.0f / fmaxf(sqrtf(ss), 1e-12f);
        *(float4*)(qL + q * C_ + lane * 4) =
            make_float4(v.x * inv, v.y * inv, v.z * inv, v.w * inv);
    }
    if (t == 0) sc[0] = 1.0f / fmaxf(LD<BF>(temp, 0), 0.01f);
    __syncthreads();

    int c0 = q * 32, half = lane >> 5, lm = lane & 31;
    float sa[4] = {0.f, 0.f, 0.f, 0.f};
    float da[K_][4];
    #pragma unroll
    for (int k = 0; k < K_; k++)
        #pragma unroll
        for (int i = 0; i < 4; i++) da[k][i] = 0.f;
    size_t gbase = (size_t)b * C_ * HW_ + (size_t)tile * P_ + lm * 4;
    #pragma unroll 4
    for (int j = 0; j < 16; j++) {
        int c = c0 + 2 * j + half;
        float4 f = LD4<BF>(feat, gbase + (size_t)c * HW_);
        sa[0] += f.x * f.x; sa[1] += f.y * f.y; sa[2] += f.z * f.z; sa[3] += f.w * f.w;
        #pragma unroll
        for (int k = 0; k < K_; k++) {
            float qv = qL[k * C_ + c];
            da[k][0] += f.x * qv; da[k][1] += f.y * qv;
            da[k][2] += f.z * qv; da[k][3] += f.w * qv;
        }
        *(uint2*)&featB[c * PS_ + 2 * lm] =
            make_uint2(packbf2(f.x, f.y), packbf2(f.z, f.w));
    }
    #pragma unroll
    for (int i = 0; i < 4; i++) sa[i] += __shfl_down(sa[i], 32, 64);
    #pragma unroll
    for (int k = 0; k < K_; k++)
        #pragma unroll
        for (int i = 0; i < 4; i++) da[k][i] += __shfl_down(da[k][i], 32, 64);

    float tinv = sc[0];
    for (int r = 0; r < 4; r++) {
        if (lane < 32) {
            red[0 * 256 + q * 32 + lane] = sa[r];
            #pragma unroll
            for (int k = 0; k < K_; k++) red[(1 + k) * 256 + q * 32 + lane] = da[k][r];
        }
        __syncthreads();
        if (t < 160) {
            int kk = t >> 5, m = t & 31, n = 4 * m + r;
            float ssum = 0.f, dsum = 0.f;
            #pragma unroll
            for (int g = 0; g < 8; g++) {
                ssum += red[0 * 256 + g * 32 + m];
                dsum += red[(1 + kk) * 256 + g * 32 + m];
            }
            float mval = LD<BF>(mask, (size_t)b * HW_ + tile * P_ + n);
            simL[kk * P_ + n] = (mval > 0.f)
                ? dsum * (tinv / fmaxf(sqrtf(ssum), 1e-12f)) : -INFINITY;
        }
        __syncthreads();
    }

    if (q < K_) {
        float s0 = simL[q * P_ + 2 * lane], s1 = simL[q * P_ + 2 * lane + 1];
        float m = fmaxf(s0, s1);
        for (int o = 32; o > 0; o >>= 1) m = fmaxf(m, __shfl_xor(m, o, 64));
        float e0 = (s0 == -INFINITY) ? 0.f : __expf(s0 - m);
        float e1 = (s1 == -INFINITY) ? 0.f : __expf(s1 - m);
        float z = e0 + e1;
        for (int o = 32; o > 0; o >>= 1) z += __shfl_xor(z, o, 64);
        wB[q * PS_ + lane] = packbf2(e0, e1);
        if (lane == 0) {
            size_t mzb = ((size_t)(b * NT_ + tile) * K_ + q) * 2;
            mz[mzb] = m; mz[mzb + 1] = z;
        }
    }
    __syncthreads();

    int r16 = lane & 15, g = lane >> 4;
    size_t pb = (size_t)(b * NT_ + tile) * (K_ * C_);
    #pragma unroll
    for (int sub = 0; sub < 2; sub++) {
        int ctile = q * 32 + sub * 16;
        f32x4 acc = {0.f, 0.f, 0.f, 0.f};
        #pragma unroll
        for (int s = 0; s < 4; s++) {
            bf16x8 a = *(const bf16x8*)(featB + (ctile + r16) * PS_ + 16 * s + 4 * g);
            bf16x8 bb = *(const bf16x8*)(wB + r16 * PS_ + 16 * s + 4 * g);
            acc = __builtin_amdgcn_mfma_f32_16x16x32_bf16(a, bb, acc, 0, 0, 0);
        }
        if (r16 < K_) {
            #pragma unroll
            for (int r = 0; r < 4; r++)
                ptp[pb + (size_t)r16 * C_ + ctile + 4 * g + r] = acc[r];
        }
    }
}
__global__ __launch_bounds__(512, 4) void k_simpt(const void* feat, const void* mask,
                                                  const void* temp, const void* pq,
                                                  float* ptp, float* mz) {
    __shared__ __attribute__((aligned(16))) float smem[20232];
    __shared__ int cnt;
    int flg = detect_bf(feat, &cnt);
    if (flg) simpt_body<true >(feat, mask, temp, pq, ptp, mz, smem);
    else     simpt_body<false>(feat, mask, temp, pq, ptp, mz, smem);
}

// ================= 2: merge + prep + div in one kernel (unchanged) ============
__device__ inline float merge_one(const float* ptp, const float* mz,
                                  int b, int kk, int c) {
    float M = -INFINITY;
    #pragma unroll 8
    for (int tl = 0; tl < NT_; tl++)
        M = fmaxf(M, mz[((size_t)(b * NT_ + tl) * K_ + kk) * 2]);
    float Zs = 0.f, acc = 0.f;
    #pragma unroll 8
    for (int tl = 0; tl < NT_; tl++) {
        size_t mzb = ((size_t)(b * NT_ + tl) * K_ + kk) * 2;
        float m_t = mz[mzb], z_t = mz[mzb + 1];
        float s = (m_t == -INFINITY) ? 0.f : __expf(m_t - M);
        Zs += z_t * s;
        acc += ptp[(size_t)(b * NT_ + tl) * (K_ * C_) + kk * C_ + c] * s;
    }
    return (Zs > 0.f) ? acc / Zs : 0.f;
}
template<bool BF>
__device__ void prep_part(const void* qw, const void* kw, const void* kb,
                          const void* vw, const void* vb, const void* ow,
                          const void* bnw, const void* bnb, const void* bnm,
                          const void* bnv, float ptv, int bk,
                          float* W2, float* b2, float* OV, float* pt, float* smem) {
    float* ptL = smem;
    float* KtL = smem + 256;
    float* VtL = smem + 512;
    float* sh  = smem + 768;
    int t = threadIdx.x;
    ptL[t] = ptv;
    pt[(size_t)bk * C_ + t] = ptv;
    __syncthreads();
    float kt = LD<BF>(kb, t), vt = LD<BF>(vb, t);
    for (int c = 0; c < C_; c += 4) {
        float4 p4 = *(float4*)(ptL + c);
        float4 kw4 = LD4<BF>(kw, (size_t)t * C_ + c);
        float4 vw4 = LD4<BF>(vw, (size_t)t * C_ + c);
        kt += kw4.x * p4.x + kw4.y * p4.y + kw4.z * p4.z + kw4.w * p4.w;
        vt += vw4.x * p4.x + vw4.y * p4.y + vw4.z * p4.z + vw4.w * p4.w;
    }
    float scale = LD<BF>(bnw, t) * rsqrtf(LD<BF>(bnv, t) + 1e-5f);
    float shift = LD<BF>(bnb, t) - LD<BF>(bnm, t) * scale;
    KtL[t] = kt * scale;
    VtL[t] = vt;
    float bpart = kt * shift;
    __syncthreads();
    float ov = 0;
    for (int c = 0; c < C_; c += 4) {
        float4 v4 = *(float4*)(VtL + c);
        float4 ow4 = LD4<BF>(ow, (size_t)t * C_ + c);
        ov += ow4.x * v4.x + ow4.y * v4.y + ow4.z * v4.z + ow4.w * v4.w;
    }
    OV[(size_t)bk * C_ + t] = ov;
    float w2 = 0;
    for (int o = 0; o < C_; o++) w2 += KtL[o] * LD<BF>(qw, (size_t)o * C_ + t);
    W2[(size_t)bk * C_ + t] = w2 * (1.0f / 16.0f);
    float bs = blk_sum(bpart, sh);
    if (t == 0) b2[bk] = bs * (1.0f / 16.0f);
}
template<bool BF>
__device__ void div_part(const float* ptp, const float* mz, const void* margin,
                         float* divpart, float* smem) {
    float* ptL = smem;
    float* rn  = smem + K_ * C_;
    float* sh  = rn + 8;
    int b = blockIdx.x - B_ * K_, t = threadIdx.x;
    for (int kk = 0; kk < K_; kk++) ptL[kk * C_ + t] = merge_one(ptp, mz, b, kk, t);
    __syncthreads();
    for (int k = 0; k < K_; k++) {
        float v = ptL[k * C_ + t];
        float s = blk_sum(v * v, sh);
        if (t == 0) rn[k] = 1.0f / fmaxf(sqrtf(s), 1e-12f);
    }
    __syncthreads();
    float m = LD<BF>(margin, 0);
    m = fminf(fmaxf(m, 0.f), 0.5f);
    int p = t >> 3, g = t & 7;
    float contrib = 0.f;
    if (p < K_ * K_) {
        int k = p / K_, j = p % K_;
        float d = 0;
        for (int c = g; c < C_; c += 8) d += ptL[k * C_ + c] * ptL[j * C_ + c];
        d += __shfl_down(d, 4, 8);
        d += __shfl_down(d, 2, 8);
        d += __shfl_down(d, 1, 8);
        if (g == 0 && k != j) contrib = fmaxf(d * rn[k] * rn[j] - m, 0.f);
    }
    float s = blk_sum(contrib, sh);
    if (t == 0) divpart[b] = s;
}
template<bool BF>
__device__ void mergeprep_body(const void* qw, const void* kw, const void* kb,
                               const void* vw, const void* vb, const void* ow,
                               const void* bnw, const void* bnb, const void* bnm,
                               const void* bnv, const void* margin,
                               const float* ptp, const float* mz,
                               float* W2, float* b2, float* OV, float* pt,
                               float* divpart, float* smem) {
    int bid = blockIdx.x, t = threadIdx.x;
    if (bid < B_ * K_) {
        int b = bid / K_, kk = bid % K_;
        float ptv = merge_one(ptp, mz, b, kk, t);
        prep_part<BF>(qw, kw, kb, vw, vb, ow, bnw, bnb, bnm, bnv,
                      ptv, bid, W2, b2, OV, pt, smem);
    } else {
        div_part<BF>(ptp, mz, margin, divpart, smem);
    }
}
__global__ void k_mergeprep(const void* feat, const void* qw, const void* kw,
                            const void* kb, const void* vw, const void* vb,
                            const void* ow, const void* bnw, const void* bnb,
                            const void* bnm, const void* bnv, const void* margin,
                            const float* ptp, const float* mz,
                            float* W2, float* b2, float* OV, float* pt, float* divpart) {
    __shared__ __attribute__((aligned(16))) float smem[K_ * C_ + 16];
    __shared__ int cnt;
    int flg = detect_bf(feat, &cnt);
    if (flg) mergeprep_body<true >(qw, kw, kb, vw, vb, ow, bnw, bnb, bnm, bnv, margin,
                                   ptp, mz, W2, b2, OV, pt, divpart, smem);
    else     mergeprep_body<false>(qw, kw, kb, vw, vb, ow, bnw, bnb, bnm, bnv, margin,
                                   ptp, mz, W2, b2, OV, pt, divpart, smem);
}

// ================= 3: fused refine-attn + residual (output via MFMA) ==========
template<bool BF>
__device__ void fin_body(const void* feat, const void* outb, const void* gamma,
                         const float* W2, const float* b2, const float* OV,
                         const float* pt, const float* divpart,
                         void* dout, float* smem) {
    u32*   featU = (u32*)smem;                  // 16896 u32 (67,584 B)
    u32*   OVp8  = featU + 256 * FS_;           // 1024 u32
    u32*   eT8   = OVp8 + 1024;                 // 512 u32
    u32*   zb    = eT8 + 512;                   // 4 u32 (zero block)
    float* pool  = (float*)(zb + 4);            // 1280 f32: W2p (ph1) / red (finalize)
    u32*   W2p   = (u32*)pool;                  // 640 u32
    float* red   = pool;                        // 1280 f32
    float* b2L   = pool + 1280;                 // 8
    int t = threadIdx.x, lane = t & 63, q = t >> 6;
    int b = blockIdx.y, tile = blockIdx.x;

    float g0 = LD<BF>(gamma, 0);
    for (int i = t; i < 640; i += 512) {
        W2p[i] = packbf2(W2[(size_t)b * 1280 + 2 * i], W2[(size_t)b * 1280 + 2 * i + 1]);
    }
    if (t < 256) {   // OVp8 row c=t: {g*OV[k][c]}k<5, g*ob[c], 0, 0
        float o0 = OV[(size_t)b * 1280 + 0 * C_ + t] * g0;
        float o1 = OV[(size_t)b * 1280 + 1 * C_ + t] * g0;
        float o2 = OV[(size_t)b * 1280 + 2 * C_ + t] * g0;
        float o3 = OV[(size_t)b * 1280 + 3 * C_ + t] * g0;
        float o4 = OV[(size_t)b * 1280 + 4 * C_ + t] * g0;
        float obv = LD<BF>(outb, t) * g0;
        OVp8[t * 4 + 0] = packbf2(o0, o1);
        OVp8[t * 4 + 1] = packbf2(o2, o3);
        OVp8[t * 4 + 2] = packbf2(o4, obv);
        OVp8[t * 4 + 3] = 0u;
    }
    if (t < 4) zb[t] = 0u;
    if (t < K_) b2L[t] = b2[b * K_ + t];
    __syncthreads();

    // ---- phase 1: logit partial dots + plain staging ----
    int c0 = q * 32, half = lane >> 5, lm = lane & 31;
    size_t gbase = (size_t)b * C_ * HW_ + (size_t)tile * P_ + lm * 4;
    float la[K_][4];
    #pragma unroll
    for (int k = 0; k < K_; k++)
        #pragma unroll
        for (int i = 0; i < 4; i++) la[k][i] = 0.f;
    #pragma unroll 4
    for (int j = 0; j < 16; j++) {
        int c = c0 + 2 * j + half;
        float4 f = LD4<BF>(feat, gbase + (size_t)c * HW_);
        #pragma unroll
        for (int k = 0; k < K_; k++) {
            u32 u = W2p[k * 128 + (c >> 1)];
            float wv = half ? hi16f(u) : lo16f(u);
            la[k][0] += f.x * wv; la[k][1] += f.y * wv;
            la[k][2] += f.z * wv; la[k][3] += f.w * wv;
        }
        *(uint2*)&featU[c * FS_ + 2 * lm] =
            make_uint2(packbf2(f.x, f.y), packbf2(f.z, f.w));
    }
    #pragma unroll
    for (int k = 0; k < K_; k++)
        #pragma unroll
        for (int i = 0; i < 4; i++) la[k][i] += __shfl_down(la[k][i], 32, 64);
    // RACE FIX (R9 bug): red aliases W2p. Ensure ALL waves finished reading W2p
    // in phase 1 before round 0 overwrites it below.
    __syncthreads();

    // ---- finalize rounds -> eT8 (bf16, slots {e0..4, 1, 0, 0}) ----
    for (int r = 0; r < 4; r++) {
        if (lane < 32) {
            #pragma unroll
            for (int k = 0; k < K_; k++) red[k * 256 + q * 32 + lane] = la[k][r];
        }
        __syncthreads();
        if (t < 32) {
            int n = 4 * t + r;
            float lg[K_];
            #pragma unroll
            for (int k = 0; k < K_; k++) {
                float s = b2L[k];
                #pragma unroll
                for (int gg = 0; gg < 8; gg++) s += red[k * 256 + gg * 32 + t];
                lg[k] = s;
            }
            float mx = fmaxf(fmaxf(fmaxf(lg[0], lg[1]), fmaxf(lg[2], lg[3])), lg[4]);
            float e0 = __expf(lg[0] - mx), e1 = __expf(lg[1] - mx),
                  e2 = __expf(lg[2] - mx), e3 = __expf(lg[3] - mx),
                  e4 = __expf(lg[4] - mx);
            float inv = 1.0f / (e0 + e1 + e2 + e3 + e4);
            eT8[n * 4 + 0] = packbf2(e0 * inv, e1 * inv);
            eT8[n * 4 + 1] = packbf2(e2 * inv, e3 * inv);
            eT8[n * 4 + 2] = packbf2(e4 * inv, 1.0f);
            eT8[n * 4 + 3] = 0u;
        }
        __syncthreads();
    }

    // ---- phase 2: output MFMA. D[m=c-sub][n=p] = OVp8 x eT8 (K=32, zero-padded)
    int r16 = lane & 15, gg = lane >> 4;
    const bf16x8 zfrag = *(const bf16x8*)zb;
    size_t base = (size_t)b * C_ * HW_ + (size_t)tile * P_;
    #pragma unroll
    for (int ct = 0; ct < 2; ct++) {
        int ctile = (q * 2 + ct) * 16;
        bf16x8 a = (gg == 0) ? *(const bf16x8*)(OVp8 + (ctile + r16) * 4) : zfrag;
        #pragma unroll
        for (int pt8 = 0; pt8 < 8; pt8++) {
            int ptile = pt8 * 16;
            bf16x8 bb = (gg == 0) ? *(const bf16x8*)(eT8 + (ptile + r16) * 4) : zfrag;
            f32x4 acc = {0.f, 0.f, 0.f, 0.f};
            acc = __builtin_amdgcn_mfma_f32_16x16x32_bf16(a, bb, acc, 0, 0, 0);
            int p = ptile + r16;
            #pragma unroll
            for (int r = 0; r < 4; r++) {
                int c = ctile + 4 * gg + r;
                u32 w = featU[c * FS_ + (p >> 1)];
                float f = (p & 1) ? hi16f(w) : lo16f(w);
                ST<BF>(dout, base + (size_t)c * HW_ + p, f + acc[r]);
            }
        }
    }
    // aux outputs (b==0 slice)
    if (b == 0) {
        const size_t enh = (size_t)B_ * C_ * HW_;
        for (int i = blockIdx.x * 512 + t; i < B_ * K_ * C_; i += NT_ * 512)
            ST<BF>(dout, enh + 1 + i, pt[i]);
        if (blockIdx.x == 0 && t == 0) {
            float s = 0;
            for (int bb2 = 0; bb2 < B_; bb2++) s += divpart[bb2];
            ST<BF>(dout, enh, s / (640.0f + 1e-5f));
        }
    }
}
__global__ __launch_bounds__(512, 4) void k_fin(const void* feat, const void* outb,
                                                const void* gamma, const float* W2,
                                                const float* b2, const float* OV,
                                                const float* pt, const float* divpart,
                                                void* dout) {
    __shared__ __attribute__((aligned(16))) float smem[19728];   // 78,912 B
    __shared__ int cnt;
    int flg = detect_bf(feat, &cnt);
    if (flg) fin_body<true >(feat, outb, gamma, W2, b2, OV, pt, divpart, dout, smem);
    else     fin_body<false>(feat, outb, gamma, W2, b2, OV, pt, divpart, dout, smem);
}

extern "C" void kernel_launch(void* const* d_in, const int* in_sizes, int n_in,
                              void* d_out, int out_size, void* d_ws, size_t ws_size,
                              hipStream_t stream) {
    const void* feat = d_in[0];
    const void* mask = d_in[1];
    const void* pq   = d_in[2];
    const void* temp = d_in[3];
    const void* marg = d_in[4];
    const void* qw   = d_in[5];
    const void* bnw  = d_in[6];
    const void* bnb  = d_in[7];
    const void* bnm  = d_in[8];
    const void* bnv  = d_in[9];
    const void* kw   = d_in[10];
    const void* kb   = d_in[11];
    const void* vw   = d_in[12];
    const void* vb   = d_in[13];
    const void* ow   = d_in[14];
    const void* ob   = d_in[15];
    const void* gm   = d_in[16];

    float* ws  = (float*)d_ws;
    float* ptp = ws;                                    // B*NT*K*C = 1,310,720
    float* mz  = ptp + (size_t)B_ * NT_ * K_ * C_;      // B*NT*K*2 = 10,240
    float* pt  = mz  + (size_t)B_ * NT_ * K_ * 2;       // 40,960
    float* W2  = pt  + B_ * K_ * C_;                    // 40,960
    float* b2  = W2  + B_ * K_ * C_;                    // 160
    float* OV  = b2  + B_ * K_;                         // 40,960
    float* dvp = OV  + B_ * K_ * C_;                    // 32

    hipLaunchKernelGGL(k_simpt, dim3(NT_, B_), dim3(512), 0, stream,
                       feat, mask, temp, pq, ptp, mz);
    hipLaunchKernelGGL(k_mergeprep, dim3(B_ * K_ + B_), dim3(256), 0, stream,
                       feat, qw, kw, kb, vw, vb, ow, bnw, bnb, bnm, bnv, marg,
                       ptp, mz, W2, b2, OV, pt, dvp);
    hipLaunchKernelGGL(k_fin, dim3(NT_, B_), dim3(512), 0, stream,
                       feat, ob, gm, W2, b2, OV, pt, dvp, d_out);
}